// Round 10
// baseline (2864.431 us; speedup 1.0000x reference)
//
#include <hip/hip_runtime.h>
#include <math.h>

typedef __attribute__((ext_vector_type(4))) float f32x4;
typedef __attribute__((ext_vector_type(8))) short short8;
typedef __attribute__((ext_vector_type(4))) unsigned int u32x4;
typedef unsigned short ushort_t;
typedef unsigned int uint_t;

// ---------------- workspace layout (float offsets) ----------------
// Encoder: Ah u16 @0 (17305600f), Al @17305600; Bh u16 @B_OFF (8921088f), Bl @BL_OFF
// Middle (A dead): C f32 @0, Dq f32 @9469952, E @18939904, Q @21037056
// Decoder: Cb16 u16 @0, Bb16 u16 @B_OFF, A16 u16 @0
static const size_t AL_OFF     = 17305600;
static const size_t C_OFF      = 0;
static const size_t D_OFF      = 9469952;
static const size_t E_OFF      = 18939904;
static const size_t Q_OFF      = 21037056;
static const size_t B_OFF      = 34611200;
static const size_t BL_OFF     = 34611200 + 8921088;
static const size_t CBT_OFF    = 52453376;
static const size_t CNORM_OFF  = 52518912;
static const size_t COUNTS_OFF = 52519936;
static const size_t SUMSQ_OFF  = 52520960;
static const size_t WT_OFF     = 52520964;

__device__ __forceinline__ ushort_t f2b(float f) {
  uint_t u = __float_as_uint(f);
  uint_t r = (u + 0x7FFFu + ((u >> 16) & 1u)) >> 16;
  return (ushort_t)r;
}
__device__ __forceinline__ float b2f(ushort_t h) {
  return __uint_as_float(((uint_t)h) << 16);
}
__device__ __forceinline__ short8 mk8(uint_t a, uint_t b, uint_t c, uint_t d) {
  u32x4 t = {a, b, c, d};
  return *(short8*)&t;
}
__device__ __forceinline__ uint_t pk2(ushort_t a, ushort_t c) {
  return (uint_t)a | ((uint_t)c << 16);
}

// ---------------- weight prep ----------------
__global__ void k_wt_conv(const float* __restrict__ w, float* __restrict__ wT,
                          int Cin, int Cout, int K) {
  const int n = Cin * Cout * K;
  for (int i = blockIdx.x * 256 + threadIdx.x; i < n; i += gridDim.x * 256) {
    const int co = i % Cout;
    const int k  = (i / Cout) % K;
    const int ci = i / (Cout * K);
    wT[i] = w[((size_t)co * Cin + ci) * K + k];
  }
}
__global__ void k_wtb(const float* __restrict__ w, ushort_t* __restrict__ wbT,
                      int Cin, int Cout) {
  const int n = 4 * Cout * Cin * 4;
  for (int i = blockIdx.x * 256 + threadIdx.x; i < n; i += gridDim.x * 256) {
    const int tap = i & 3;
    const int ci  = (i >> 2) % Cin;
    const int co  = ((i >> 2) / Cin) % Cout;
    const int ph  = (i >> 2) / (Cin * Cout);
    const int ey = ph >> 1, ex = ph & 1;
    const int ty = tap >> 1, tx = tap & 1;
    const int kidx = (3 - 2 * ty - ey) * 4 + (3 - 2 * tx - ex);
    wbT[i] = f2b(w[((size_t)ci * Cout + co) * 16 + kidx]);
  }
}
__global__ void k_wsplit(const float* __restrict__ w, ushort_t* __restrict__ wh,
                         ushort_t* __restrict__ wl, int n) {
  for (int i = blockIdx.x * 256 + threadIdx.x; i < n; i += gridDim.x * 256) {
    const float v = w[i];
    const ushort_t h = f2b(v);
    wh[i] = h;
    wl[i] = f2b(v - b2f(h));
  }
}
__global__ void k_cbt(const float* __restrict__ cb, float* __restrict__ cbT,
                      float* __restrict__ cnorm) {
  const int c = blockIdx.x * 256 + threadIdx.x;
  float s = 0.0f;
  for (int ci = 0; ci < 64; ++ci) {
    const float v = cb[(size_t)c * 64 + ci];
    s += v * v;
    cbT[(size_t)ci * 1024 + c] = v;
  }
  cnorm[c] = s;
}

// ---------------- enc0: conv 4x4 s2 p1, Cin=3, staged; writes SPLIT u16 planes ----------
__global__ __launch_bounds__(256) void k_conv4s2_s3(
    const float* __restrict__ in, const float* __restrict__ wT,
    const float* __restrict__ bias, ushort_t* __restrict__ oh,
    ushort_t* __restrict__ ol) {
  const int b   = blockIdx.z;
  const int co0 = blockIdx.y << 4;
  const int oy0 = (blockIdx.x >> 2) << 5;
  const int ox0 = (blockIdx.x & 3) << 5;
  const int tid = threadIdx.x;
  const int ty = tid >> 4, tx = tid & 15;
  __shared__ float tin[3][66][67];
  float acc[4][16];
#pragma unroll
  for (int p = 0; p < 4; ++p)
#pragma unroll
    for (int co = 0; co < 16; ++co) acc[p][co] = 0.0f;

  const int iy0 = (oy0 << 1) - 1, ix0 = (ox0 << 1) - 1;
  for (int c = 0; c < 3; ++c) {
    const float* ip = in + (size_t)(b * 3 + c) * 65536;
    for (int j = tid; j < 66 * 66; j += 256) {
      const int r = j / 66, col = j - r * 66;
      const int iy = iy0 + r, ix = ix0 + col;
      float v = 0.0f;
      if ((unsigned)iy < 256u && (unsigned)ix < 256u) v = ip[iy * 256 + ix];
      tin[c][r][col] = v;
    }
  }
  __syncthreads();
#pragma unroll
  for (int c = 0; c < 3; ++c) {
    const float* wp = wT + (size_t)c * 16 * 64 + co0;
#pragma unroll
    for (int ky = 0; ky < 4; ++ky)
#pragma unroll
      for (int kx = 0; kx < 4; ++kx) {
        const float v0 = tin[c][2 * ty + ky][2 * tx + kx];
        const float v1 = tin[c][2 * ty + ky][2 * tx + 32 + kx];
        const float v2 = tin[c][2 * ty + 32 + ky][2 * tx + kx];
        const float v3 = tin[c][2 * ty + 32 + ky][2 * tx + 32 + kx];
        const float* wk = wp + (ky * 4 + kx) * 64;
#pragma unroll
        for (int co = 0; co < 16; ++co) {
          const float wv = wk[co];
          acc[0][co] = fmaf(v0, wv, acc[0][co]);
          acc[1][co] = fmaf(v1, wv, acc[1][co]);
          acc[2][co] = fmaf(v2, wv, acc[2][co]);
          acc[3][co] = fmaf(v3, wv, acc[3][co]);
        }
      }
  }
#pragma unroll
  for (int co = 0; co < 16; ++co) {
    const float bv = bias[co0 + co];
    ushort_t* oph = oh + (size_t)(b * 64 + co0 + co) * 16900;
    ushort_t* opl = ol + (size_t)(b * 64 + co0 + co) * 16900;
    const int idx[4] = {(oy0 + ty + 1) * 130 + ox0 + tx + 1,
                        (oy0 + ty + 1) * 130 + ox0 + tx + 17,
                        (oy0 + ty + 17) * 130 + ox0 + tx + 1,
                        (oy0 + ty + 17) * 130 + ox0 + tx + 17};
#pragma unroll
    for (int p = 0; p < 4; ++p) {
      const float v = fmaxf(acc[p][co] + bv, 0.0f);
      const ushort_t h = f2b(v);
      oph[idx[p]] = h;
      opl[idx[p]] = f2b(v - b2f(h));
    }
  }
}

// ---------------- LDS-FREE split-bf16 MFMA conv 4x4 s2 p1 (encoder) ----------------
// Direct global->fragment loads; no LDS, no barriers. Fragment index math identical to the
// verified R9 staging (lane(arow,ag) <-> staging thread(spx,kg)).
template <int WSHIFT, int CIN, int COUT, int WP, int INSTRIDE, int WOP, int OUTSTRIDE,
          int OUT_SPLIT>
__global__ __launch_bounds__(256) void k_conv4s2_dmfma(
    const ushort_t* __restrict__ inh, const ushort_t* __restrict__ inl,
    const ushort_t* __restrict__ wbh, const ushort_t* __restrict__ wbl,
    const float* __restrict__ bias, float* __restrict__ outf,
    ushort_t* __restrict__ oth, ushort_t* __restrict__ otl) {
  constexpr int W = 1 << WSHIFT;
  constexpr int NCH = CIN / 2;
  const int tid = threadIdx.x;
  const int b = blockIdx.z;
  const int co_b0 = blockIdx.y << 6;
  const int pxb0 = blockIdx.x << 6;
  const int lane = tid & 63, wid = tid >> 6;
  const int wm = wid & 1, wn = wid >> 1;
  const int arow = lane & 15, ag = lane >> 4;

  size_t aoff[2];
#pragma unroll
  for (int m = 0; m < 2; ++m) {
    const int px = pxb0 + wm * 32 + m * 16 + arow;
    const int sy = px >> WSHIFT, sx = px & (W - 1);
    aoff[m] = (size_t)(b * CIN + (ag >> 1)) * INSTRIDE
            + (size_t)(2 * sy + 2 * (ag & 1)) * WP + 2 * sx;
  }
  size_t boff[2];
#pragma unroll
  for (int n = 0; n < 2; ++n)
    boff[n] = (size_t)(co_b0 + wn * 32 + n * 16 + arow) * (CIN * 16) + ag * 8;

  f32x4 acc[2][2];
#pragma unroll
  for (int m = 0; m < 2; ++m)
#pragma unroll
    for (int n = 0; n < 2; ++n) acc[m][n] = (f32x4){0.f, 0.f, 0.f, 0.f};

#pragma unroll 2
  for (int ch = 0; ch < NCH; ++ch) {
    short8 ah[2], al[2], bh[2], bl[2];
#pragma unroll
    for (int m = 0; m < 2; ++m) {
      const ushort_t* ph = inh + aoff[m] + (size_t)(2 * ch) * INSTRIDE;
      const ushort_t* pl = inl + aoff[m] + (size_t)(2 * ch) * INSTRIDE;
      ah[m] = mk8(*(const uint_t*)(ph), *(const uint_t*)(ph + 2),
                  *(const uint_t*)(ph + WP), *(const uint_t*)(ph + WP + 2));
      al[m] = mk8(*(const uint_t*)(pl), *(const uint_t*)(pl + 2),
                  *(const uint_t*)(pl + WP), *(const uint_t*)(pl + WP + 2));
    }
#pragma unroll
    for (int n = 0; n < 2; ++n) {
      bh[n] = *(const short8*)(wbh + boff[n] + ch * 32);
      bl[n] = *(const short8*)(wbl + boff[n] + ch * 32);
    }
#pragma unroll
    for (int m = 0; m < 2; ++m)
#pragma unroll
      for (int n = 0; n < 2; ++n) {
        acc[m][n] = __builtin_amdgcn_mfma_f32_16x16x32_bf16(ah[m], bh[n], acc[m][n], 0, 0, 0);
        acc[m][n] = __builtin_amdgcn_mfma_f32_16x16x32_bf16(ah[m], bl[n], acc[m][n], 0, 0, 0);
        acc[m][n] = __builtin_amdgcn_mfma_f32_16x16x32_bf16(al[m], bh[n], acc[m][n], 0, 0, 0);
      }
  }

#pragma unroll
  for (int m = 0; m < 2; ++m)
#pragma unroll
    for (int n = 0; n < 2; ++n) {
      const int col = co_b0 + wn * 32 + n * 16 + arow;
      const float bv = bias[col];
#pragma unroll
      for (int r = 0; r < 4; ++r) {
        const int pxl = pxb0 + wm * 32 + m * 16 + ag * 4 + r;
        const int yy = pxl >> WSHIFT, xx = pxl & (W - 1);
        const float v = fmaxf(acc[m][n][r] + bv, 0.0f);
        if constexpr (OUT_SPLIT) {
          const size_t o = (size_t)(b * COUT + col) * OUTSTRIDE + (size_t)(yy + 1) * WOP + xx + 1;
          const ushort_t h = f2b(v);
          oth[o] = h;
          otl[o] = f2b(v - b2f(h));
        } else {
          outf[(size_t)(b * COUT + col) * OUTSTRIDE + (size_t)(yy + 1) * WOP + xx + 1] = v;
        }
      }
    }
}

// ---------------- conv3x3 p1 (256->64 @32x32), px-parallel (fp32) ----------
__global__ __launch_bounds__(256) void k_conv3x3_px(
    const float* __restrict__ in, const float* __restrict__ wT,
    const float* __restrict__ bias, float* __restrict__ out) {
  const int b   = blockIdx.z;
  const int co0 = blockIdx.y << 4;
  const int px  = blockIdx.x * 256 + threadIdx.x;
  const int y = px >> 5, x = px & 31;
  const float* ip = in + (size_t)b * 256 * 1156 + (size_t)y * 34 + x;
  float acc[16];
#pragma unroll
  for (int co = 0; co < 16; ++co) acc[co] = 0.0f;
  const float* wp = wT + co0;
  for (int ci = 0; ci < 256; ++ci) {
    float v[9];
#pragma unroll
    for (int dy = 0; dy < 3; ++dy)
#pragma unroll
      for (int dx = 0; dx < 3; ++dx) v[dy * 3 + dx] = fmaxf(ip[dy * 34 + dx], 0.0f);
    ip += 1156;
    const float* wk = wp;
#pragma unroll
    for (int t = 0; t < 9; ++t) {
      const float vv = v[t];
#pragma unroll
      for (int co = 0; co < 16; ++co) acc[co] = fmaf(vv, wk[co], acc[co]);
      wk += 64;
    }
    wp += 9 * 64;
  }
  float* op = out + (size_t)(b * 64 + co0) * 1024 + px;
#pragma unroll
  for (int co = 0; co < 16; ++co) op[(size_t)co * 1024] = acc[co] + bias[co0 + co];
}

// ---------------- conv1x1 px-parallel; OUT_BF16 writes u16 plane ----------
template <int IN_RELU, int HAS_RES, int IN_PAD, int OUT_PAD, int OUT_BF16>
__global__ __launch_bounds__(256) void k_conv1x1_px(
    const float* __restrict__ in, const float* __restrict__ wT,
    const float* __restrict__ bias, const float* __restrict__ res,
    float* __restrict__ out, int Cin, int Cout) {
  const int b   = blockIdx.z;
  const int co0 = blockIdx.y << 4;
  const int px  = blockIdx.x * 256 + threadIdx.x;
  const int ppad = 35 + px + 2 * (px >> 5);
  const int ioff = IN_PAD ? ppad : px;
  const int istr = IN_PAD ? 1156 : 1024;
  const int ooff = OUT_PAD ? ppad : px;
  const int ostr = OUT_PAD ? 1156 : 1024;
  float acc[16];
#pragma unroll
  for (int co = 0; co < 16; ++co) acc[co] = 0.0f;
  const float* ip = in + (size_t)b * Cin * istr + ioff;
  const float* wp = wT + co0;
  for (int ci = 0; ci < Cin; ++ci) {
    float v = *ip;
    if (IN_RELU) v = fmaxf(v, 0.0f);
    ip += istr;
#pragma unroll
    for (int co = 0; co < 16; ++co) acc[co] = fmaf(v, wp[co], acc[co]);
    wp += Cout;
  }
  const float* rp = res + (size_t)(b * Cout + co0) * ostr + ooff;
#pragma unroll
  for (int co = 0; co < 16; ++co) {
    float r = acc[co] + bias[co0 + co];
    if (HAS_RES) r += rp[(size_t)co * ostr];
    if constexpr (OUT_BF16) {
      ushort_t* ob = ((ushort_t*)out) + (size_t)(b * Cout + co0) * ostr + ooff;
      ob[(size_t)co * ostr] = f2b(r);
    } else {
      float* op = out + (size_t)(b * Cout + co0) * ostr + ooff;
      op[(size_t)co * ostr] = r;
    }
  }
}

// ---------------- LDS-FREE MFMA bf16 tconv (phase-decomposed implicit GEMM) ----------------
// OUTMODE: 0 = u16 bf16 padded plane (relu), 1 = FINAL fused 1x1 -> fp32 d_out (one barrier)
template <int PXB, int COB, int WSHIFT, int CIN, int COUT, int WP, int INSTRIDE,
          int WOP, int OUTSTRIDE, int OUTMODE>
__global__ __launch_bounds__(256) void k_tconv_dmfma(
    const ushort_t* __restrict__ in, const ushort_t* __restrict__ wbT,
    const float* __restrict__ bias, const float* __restrict__ ow,
    const float* __restrict__ ob, ushort_t* __restrict__ outp,
    float* __restrict__ outf) {
  constexpr int W = 1 << WSHIFT;
  constexpr int NCH = CIN / 8;
  constexpr int NWM = PXB / 32;
  __shared__ float pxco[OUTMODE ? PXB : 1][33];

  const int tid = threadIdx.x;
  const int b = blockIdx.z;
  const int phase = blockIdx.y & 3;
  const int ey = phase >> 1, ex = phase & 1;
  const int co_b0 = (blockIdx.y >> 2) * COB;
  const int pxb0 = blockIdx.x * PXB;
  const int lane = tid & 63, wid = tid >> 6;
  const int wm = wid % NWM, wn = wid / NWM;
  const int arow = lane & 15, ag = lane >> 4;

  size_t aoff[2];
#pragma unroll
  for (int m = 0; m < 2; ++m) {
    const int px = pxb0 + wm * 32 + m * 16 + arow;
    const int sy = px >> WSHIFT, sx = px & (W - 1);
    aoff[m] = (size_t)(b * CIN + ag * 2) * INSTRIDE + (size_t)(sy + ey) * WP + (sx + ex);
  }
  size_t boff[2];
#pragma unroll
  for (int n = 0; n < 2; ++n)
    boff[n] = ((size_t)(phase * COUT + co_b0 + wn * 32 + n * 16 + arow) * CIN) * 4 + ag * 8;

  f32x4 acc[2][2];
#pragma unroll
  for (int m = 0; m < 2; ++m)
#pragma unroll
    for (int n = 0; n < 2; ++n) acc[m][n] = (f32x4){0.f, 0.f, 0.f, 0.f};

#pragma unroll 2
  for (int ch = 0; ch < NCH; ++ch) {
    short8 a[2], bb[2];
#pragma unroll
    for (int m = 0; m < 2; ++m) {
      uint_t w[4];
#pragma unroll
      for (int cs = 0; cs < 2; ++cs) {
        const ushort_t* p = in + aoff[m] + (size_t)(ch * 8 + cs) * INSTRIDE;
        w[cs * 2]     = pk2(p[0], p[1]);
        w[cs * 2 + 1] = pk2(p[WP], p[WP + 1]);
      }
      a[m] = mk8(w[0], w[1], w[2], w[3]);
    }
#pragma unroll
    for (int n = 0; n < 2; ++n)
      bb[n] = *(const short8*)(wbT + boff[n] + ch * 32);
    acc[0][0] = __builtin_amdgcn_mfma_f32_16x16x32_bf16(a[0], bb[0], acc[0][0], 0, 0, 0);
    acc[0][1] = __builtin_amdgcn_mfma_f32_16x16x32_bf16(a[0], bb[1], acc[0][1], 0, 0, 0);
    acc[1][0] = __builtin_amdgcn_mfma_f32_16x16x32_bf16(a[1], bb[0], acc[1][0], 0, 0, 0);
    acc[1][1] = __builtin_amdgcn_mfma_f32_16x16x32_bf16(a[1], bb[1], acc[1][1], 0, 0, 0);
  }

  if constexpr (!OUTMODE) {
#pragma unroll
    for (int m = 0; m < 2; ++m)
#pragma unroll
      for (int n = 0; n < 2; ++n) {
        const int col = co_b0 + wn * 32 + n * 16 + arow;
        const float bv = bias[col];
        ushort_t* obase = outp + (size_t)(b * COUT + col) * OUTSTRIDE;
#pragma unroll
        for (int r = 0; r < 4; ++r) {
          const int pxl = pxb0 + wm * 32 + m * 16 + ag * 4 + r;
          const int yy = pxl >> WSHIFT, xx = pxl & (W - 1);
          obase[(size_t)(2 * yy + ey + 1) * WOP + (2 * xx + ex + 1)] =
              f2b(fmaxf(acc[m][n][r] + bv, 0.0f));
        }
      }
  } else {
#pragma unroll
    for (int m = 0; m < 2; ++m)
#pragma unroll
      for (int n = 0; n < 2; ++n) {
        const int col = wn * 32 + n * 16 + arow;
        const float bv = bias[col];
#pragma unroll
        for (int r = 0; r < 4; ++r) {
          const int pxl = wm * 32 + m * 16 + ag * 4 + r;
          pxco[pxl][col] = fmaxf(acc[m][n][r] + bv, 0.0f);
        }
      }
    __syncthreads();
    if (tid < PXB) {
      const int pxg = pxb0 + tid;
      const int yy = pxg >> WSHIFT, xx = pxg & (W - 1);
      const int oy = 2 * yy + ey, ox = 2 * xx + ex;
      float o0 = ob[0], o1 = ob[1], o2 = ob[2];
#pragma unroll
      for (int co = 0; co < 32; ++co) {
        const float v = pxco[tid][co];
        o0 = fmaf(ow[co], v, o0);
        o1 = fmaf(ow[32 + co], v, o1);
        o2 = fmaf(ow[64 + co], v, o2);
      }
      outf[((size_t)(b * 3 + 0) * 256 + oy) * 256 + ox] = o0;
      outf[((size_t)(b * 3 + 1) * 256 + oy) * 256 + ox] = o1;
      outf[((size_t)(b * 3 + 2) * 256 + oy) * 256 + ox] = o2;
    }
  }
}

// ---------------- VQ (fp32 exact) ----------------
__global__ __launch_bounds__(256) void k_vq(
    const float* __restrict__ zlat, const float* __restrict__ cbT,
    const float* __restrict__ cnorm, const float* __restrict__ cb,
    float* __restrict__ q, float* __restrict__ counts, float* __restrict__ sumsq) {
  const int tid = threadIdx.x;
  const int px0 = blockIdx.x << 4;
  const int b   = px0 >> 10;
  const int pl0 = px0 & 1023;
  __shared__ float zT[64][17];
  __shared__ float rd[16][256];
  __shared__ int   ri[16][256];
  for (int j = tid; j < 1024; j += 256) {
    const int ci = j >> 4, p = j & 15;
    zT[ci][p] = zlat[(size_t)(b * 64 + ci) * 1024 + pl0 + p];
  }
  __syncthreads();
  float dot[4][16];
#pragma unroll
  for (int k = 0; k < 4; ++k)
#pragma unroll
    for (int p = 0; p < 16; ++p) dot[k][p] = 0.0f;
  for (int ci = 0; ci < 64; ++ci) {
    float z[16];
#pragma unroll
    for (int p = 0; p < 16; ++p) z[p] = zT[ci][p];
#pragma unroll
    for (int k = 0; k < 4; ++k) {
      const float cv = cbT[(size_t)ci * 1024 + (k << 8) + tid];
#pragma unroll
      for (int p = 0; p < 16; ++p) dot[k][p] = fmaf(cv, z[p], dot[k][p]);
    }
  }
  float bd[16]; int bi[16];
#pragma unroll
  for (int p = 0; p < 16; ++p) { bd[p] = 3.4e38f; bi[p] = 0; }
#pragma unroll
  for (int k = 0; k < 4; ++k) {
    const int c = (k << 8) + tid;
    const float cn = cnorm[c];
#pragma unroll
    for (int p = 0; p < 16; ++p) {
      const float d = cn - 2.0f * dot[k][p];
      if (d < bd[p]) { bd[p] = d; bi[p] = c; }
    }
  }
#pragma unroll
  for (int p = 0; p < 16; ++p) { rd[p][tid] = bd[p]; ri[p][tid] = bi[p]; }
  __syncthreads();
  for (int s = 128; s >= 1; s >>= 1) {
    if (tid < s) {
#pragma unroll
      for (int p = 0; p < 16; ++p) {
        const float d2 = rd[p][tid + s]; const int i2 = ri[p][tid + s];
        const float d1 = rd[p][tid];     const int i1 = ri[p][tid];
        if (d2 < d1 || (d2 == d1 && i2 < i1)) { rd[p][tid] = d2; ri[p][tid] = i2; }
      }
    }
    __syncthreads();
  }
  if (tid < 16) atomicAdd(&counts[ri[tid][0]], 1.0f);
  const int p    = tid >> 4;
  const int best = ri[p][0];
  const int cb0  = (tid & 15) << 2;
  float ss = 0.0f;
  float* qp = q + (size_t)b * 65536 + pl0 + p;
#pragma unroll
  for (int cc = 0; cc < 4; ++cc) {
    const int ci = cb0 + cc;
    const float qv = cb[(size_t)best * 64 + ci];
    const float zv = zT[ci][p];
    const float df = qv - zv;
    ss += df * df;
    qp[(size_t)ci * 1024] = qv;
  }
#pragma unroll
  for (int o = 32; o > 0; o >>= 1) ss += __shfl_down(ss, o);
  if ((tid & 63) == 0) atomicAdd(sumsq, ss);
}

__global__ void k_final(const float* __restrict__ counts, const float* __restrict__ sumsq,
                        float* __restrict__ out2) {
  const int tid = threadIdx.x;
  float h = 0.0f;
  for (int k = tid; k < 1024; k += 256) {
    const float pr = counts[k] * (1.0f / 32768.0f);
    h -= pr * logf(pr + 1e-10f);
  }
#pragma unroll
  for (int o = 32; o > 0; o >>= 1) h += __shfl_down(h, o);
  __shared__ float hs[4];
  if ((tid & 63) == 0) hs[tid >> 6] = h;
  __syncthreads();
  if (tid == 0) {
    out2[0] = 1.25f * sumsq[0] * (1.0f / 2097152.0f);
    out2[1] = expf(hs[0] + hs[1] + hs[2] + hs[3]);
  }
}

// ---------------- launcher ----------------
extern "C" void kernel_launch(void* const* d_in, const int* in_sizes, int n_in,
                              void* d_out, int out_size, void* d_ws, size_t ws_size,
                              hipStream_t stream) {
  const float* x        = (const float*)d_in[0];
  const float* enc_w0   = (const float*)d_in[1];
  const float* enc_b0   = (const float*)d_in[2];
  const float* enc_w1   = (const float*)d_in[3];
  const float* enc_b1   = (const float*)d_in[4];
  const float* enc_w2   = (const float*)d_in[5];
  const float* enc_b2   = (const float*)d_in[6];
  const float* er0w1    = (const float*)d_in[7];
  const float* er0b1    = (const float*)d_in[8];
  const float* er0w2    = (const float*)d_in[9];
  const float* er0b2    = (const float*)d_in[10];
  const float* er1w1    = (const float*)d_in[11];
  const float* er1b1    = (const float*)d_in[12];
  const float* er1w2    = (const float*)d_in[13];
  const float* er1b2    = (const float*)d_in[14];
  const float* eadj_w   = (const float*)d_in[15];
  const float* eadj_b   = (const float*)d_in[16];
  const float* codebook = (const float*)d_in[17];
  const float* dadj_w   = (const float*)d_in[18];
  const float* dadj_b   = (const float*)d_in[19];
  const float* dr0w1    = (const float*)d_in[20];
  const float* dr0b1    = (const float*)d_in[21];
  const float* dr0w2    = (const float*)d_in[22];
  const float* dr0b2    = (const float*)d_in[23];
  const float* dr1w1    = (const float*)d_in[24];
  const float* dr1b1    = (const float*)d_in[25];
  const float* dr1w2    = (const float*)d_in[26];
  const float* dr1b2    = (const float*)d_in[27];
  const float* tw0      = (const float*)d_in[28];
  const float* tb0      = (const float*)d_in[29];
  const float* tw1      = (const float*)d_in[30];
  const float* tb1      = (const float*)d_in[31];
  const float* tw2      = (const float*)d_in[32];
  const float* tb2      = (const float*)d_in[33];
  const float* out_w    = (const float*)d_in[34];
  const float* out_b    = (const float*)d_in[35];

  float* ws = (float*)d_ws;
  ushort_t* Ah   = (ushort_t*)ws;
  ushort_t* Al   = (ushort_t*)(ws + AL_OFF);
  ushort_t* Bh   = (ushort_t*)(ws + B_OFF);
  ushort_t* Bl   = (ushort_t*)(ws + BL_OFF);
  ushort_t* Cb16 = (ushort_t*)ws;
  ushort_t* Bb16 = (ushort_t*)(ws + B_OFF);
  ushort_t* A16  = (ushort_t*)ws;
  float* C      = ws + C_OFF;
  float* Dq     = ws + D_OFF;
  float* E      = ws + E_OFF;
  float* Q      = ws + Q_OFF;
  float* cbT    = ws + CBT_OFF;
  float* cnorm  = ws + CNORM_OFF;
  float* counts = ws + COUNTS_OFF;
  float* sumsq  = ws + SUMSQ_OFF;

  size_t o = WT_OFF;
  float* wt_enc0  = ws + o; o += (size_t)3 * 16 * 64;
  float* wt_er0w1 = ws + o; o += (size_t)256 * 9 * 64;
  float* wt_er0w2 = ws + o; o += (size_t)64 * 256;
  float* wt_er1w1 = ws + o; o += (size_t)256 * 9 * 64;
  float* wt_er1w2 = ws + o; o += (size_t)64 * 256;
  float* wt_eadj  = ws + o; o += (size_t)256 * 64;
  float* wt_dadj  = ws + o; o += (size_t)64 * 256;
  float* wt_dr0w1 = ws + o; o += (size_t)256 * 9 * 64;
  float* wt_dr0w2 = ws + o; o += (size_t)64 * 256;
  float* wt_dr1w1 = ws + o; o += (size_t)256 * 9 * 64;
  float* wt_dr1w2 = ws + o; o += (size_t)64 * 256;
  ushort_t* wbT0 = (ushort_t*)(ws + o); o += 262144;  // 4*128*256*4 u16
  ushort_t* wbT1 = (ushort_t*)(ws + o); o += 65536;   // 4*64*128*4  u16
  ushort_t* wbT2 = (ushort_t*)(ws + o); o += 16384;   // 4*32*64*4   u16
  ushort_t* wsh1 = (ushort_t*)(ws + o); o += 65536;   // 128*64*16 u16
  ushort_t* wsl1 = (ushort_t*)(ws + o); o += 65536;
  ushort_t* wsh2 = (ushort_t*)(ws + o); o += 262144;  // 256*128*16 u16
  ushort_t* wsl2 = (ushort_t*)(ws + o); o += 262144;

  float* fout = (float*)d_out;

  #define GB(n) (((n) + 255) / 256)
  hipMemsetAsync(ws, 0, WT_OFF * sizeof(float), stream);

  k_wt_conv<<<GB(3 * 64 * 16), 256, 0, stream>>>(enc_w0, wt_enc0, 3, 64, 16);
  k_wt_conv<<<GB(256 * 64 * 9), 256, 0, stream>>>(er0w1, wt_er0w1, 256, 64, 9);
  k_wt_conv<<<GB(64 * 256), 256, 0, stream>>>(er0w2, wt_er0w2, 64, 256, 1);
  k_wt_conv<<<GB(256 * 64 * 9), 256, 0, stream>>>(er1w1, wt_er1w1, 256, 64, 9);
  k_wt_conv<<<GB(64 * 256), 256, 0, stream>>>(er1w2, wt_er1w2, 64, 256, 1);
  k_wt_conv<<<GB(256 * 64), 256, 0, stream>>>(eadj_w, wt_eadj, 256, 64, 1);
  k_wt_conv<<<GB(64 * 256), 256, 0, stream>>>(dadj_w, wt_dadj, 64, 256, 1);
  k_wt_conv<<<GB(256 * 64 * 9), 256, 0, stream>>>(dr0w1, wt_dr0w1, 256, 64, 9);
  k_wt_conv<<<GB(64 * 256), 256, 0, stream>>>(dr0w2, wt_dr0w2, 64, 256, 1);
  k_wt_conv<<<GB(256 * 64 * 9), 256, 0, stream>>>(dr1w1, wt_dr1w1, 256, 64, 9);
  k_wt_conv<<<GB(64 * 256), 256, 0, stream>>>(dr1w2, wt_dr1w2, 64, 256, 1);
  k_wtb<<<GB(524288), 256, 0, stream>>>(tw0, wbT0, 256, 128);
  k_wtb<<<GB(131072), 256, 0, stream>>>(tw1, wbT1, 128, 64);
  k_wtb<<<GB(32768), 256, 0, stream>>>(tw2, wbT2, 64, 32);
  k_wsplit<<<GB(131072), 256, 0, stream>>>(enc_w1, wsh1, wsl1, 131072);
  k_wsplit<<<GB(524288), 256, 0, stream>>>(enc_w2, wsh2, wsl2, 524288);
  k_cbt<<<4, 256, 0, stream>>>(codebook, cbT, cnorm);

  // ---------- encoder (split-bf16 MFMA ~ fp32 accuracy; protects VQ argmin) ----------
  k_conv4s2_s3<<<dim3(16, 4, 32), 256, 0, stream>>>(x, wt_enc0, enc_b0, Ah, Al);
  k_conv4s2_dmfma<6, 64, 128, 130, 16900, 66, 4356, 1>
      <<<dim3(64, 2, 32), 256, 0, stream>>>(Ah, Al, wsh1, wsl1, enc_b1, nullptr, Bh, Bl);
  hipMemsetAsync(ws, 0, (size_t)18939904 * sizeof(float), stream);  // C+Dq halos (A dead)
  k_conv4s2_dmfma<5, 128, 256, 66, 4356, 34, 1156, 0>
      <<<dim3(16, 4, 32), 256, 0, stream>>>(Bh, Bl, wsh2, wsl2, enc_b2, C, nullptr, nullptr);
  k_conv3x3_px<<<dim3(4, 4, 32), 256, 0, stream>>>(C, wt_er0w1, er0b1, E);
  k_conv1x1_px<1, 1, 0, 1, 0><<<dim3(4, 16, 32), 256, 0, stream>>>(E, wt_er0w2, er0b2, C, Dq, 64, 256);
  k_conv3x3_px<<<dim3(4, 4, 32), 256, 0, stream>>>(Dq, wt_er1w1, er1b1, E);
  k_conv1x1_px<1, 1, 0, 1, 0><<<dim3(4, 16, 32), 256, 0, stream>>>(E, wt_er1w2, er1b2, Dq, C, 64, 256);
  k_conv1x1_px<0, 0, 1, 0, 0><<<dim3(4, 4, 32), 256, 0, stream>>>(C, wt_eadj, eadj_b, nullptr, E, 256, 64);
  // ---------- VQ ----------
  k_vq<<<2048, 256, 0, stream>>>(E, cbT, cnorm, codebook, Q, counts, sumsq);
  // ---------- decoder ----------
  k_conv1x1_px<0, 0, 0, 1, 0><<<dim3(4, 16, 32), 256, 0, stream>>>(Q, wt_dadj, dadj_b, nullptr, C, 64, 256);
  k_conv3x3_px<<<dim3(4, 4, 32), 256, 0, stream>>>(C, wt_dr0w1, dr0b1, E);
  k_conv1x1_px<1, 1, 0, 1, 0><<<dim3(4, 16, 32), 256, 0, stream>>>(E, wt_dr0w2, dr0b2, C, Dq, 64, 256);
  k_conv3x3_px<<<dim3(4, 4, 32), 256, 0, stream>>>(Dq, wt_dr1w1, dr1b1, E);
  hipMemsetAsync(ws, 0, (size_t)4734976 * sizeof(float), stream);   // Cb16 halos (fp32 C dead)
  k_conv1x1_px<1, 1, 0, 1, 1><<<dim3(4, 16, 32), 256, 0, stream>>>(E, wt_dr1w2, dr1b2, Dq, (float*)Cb16, 64, 256);
  hipMemsetAsync(ws + B_OFF, 0, (size_t)8921088 * sizeof(float), stream);  // Bb16 halos
  k_tconv_dmfma<64, 64, 5, 256, 128, 34, 1156, 66, 4356, 0>
      <<<dim3(16, 8, 32), 256, 0, stream>>>(Cb16, wbT0, tb0, nullptr, nullptr, Bb16, nullptr);
  hipMemsetAsync(ws, 0, (size_t)17305600 * sizeof(float), stream);  // A16 halos (Cb16 dead)
  k_tconv_dmfma<64, 64, 6, 128, 64, 66, 4356, 130, 16900, 0>
      <<<dim3(64, 4, 32), 256, 0, stream>>>(Bb16, wbT1, tb1, nullptr, nullptr, A16, nullptr);
  k_tconv_dmfma<128, 32, 7, 64, 32, 130, 16900, 0, 0, 1>
      <<<dim3(128, 4, 32), 256, 0, stream>>>(A16, wbT2, tb2, out_w, out_b, nullptr, fout);
  k_final<<<1, 256, 0, stream>>>(counts, sumsq, fout + 6291456);
  #undef GB
}

// Round 11
// 2269.413 us; speedup vs baseline: 1.2622x; 1.2622x over previous
//
#include <hip/hip_runtime.h>
#include <math.h>

typedef __attribute__((ext_vector_type(4))) float f32x4;
typedef __attribute__((ext_vector_type(8))) short short8;
typedef __attribute__((ext_vector_type(4))) unsigned int u32x4;
typedef unsigned short ushort_t;
typedef unsigned int uint_t;

// ---------------- workspace layout (float offsets), lifetime-packed, PADDED activations ----
static const size_t A_OFF      = 0;
static const size_t C_OFF      = 0;
static const size_t D_OFF      = 9469952;
static const size_t E_OFF      = 18939904;
static const size_t Q_OFF      = 21037056;
static const size_t B_OFF      = 34611200;
static const size_t CBT_OFF    = 52453376;  // 64*1024
static const size_t CNORM_OFF  = 52518912;  // 1024
static const size_t COUNTS_OFF = 52519936;  // 1024
static const size_t SUMSQ_OFF  = 52520960;  // 1 (+3)
static const size_t WT_OFF     = 52520964;  // transposed weights + bf16/split weights

__device__ __forceinline__ ushort_t f2b(float f) {
  uint_t u = __float_as_uint(f);
  uint_t r = (u + 0x7FFFu + ((u >> 16) & 1u)) >> 16;
  return (ushort_t)r;
}
__device__ __forceinline__ float b2f(ushort_t h) {
  return __uint_as_float(((uint_t)h) << 16);
}

// ---------------- weight prep ----------------
// [Cout,Cin,K] -> [Cin,K,Cout]  (fp32, for fp32 kernels)
__global__ void k_wt_conv(const float* __restrict__ w, float* __restrict__ wT,
                          int Cin, int Cout, int K) {
  const int n = Cin * Cout * K;
  for (int i = blockIdx.x * 256 + threadIdx.x; i < n; i += gridDim.x * 256) {
    const int co = i % Cout;
    const int k  = (i / Cout) % K;
    const int ci = i / (Cout * K);
    wT[i] = w[((size_t)co * Cin + ci) * K + k];
  }
}
// tconv weight [Cin][Cout][16] -> bf16 wbT[phase][co][ci*4+tap]
__global__ void k_wtb(const float* __restrict__ w, ushort_t* __restrict__ wbT,
                      int Cin, int Cout) {
  const int n = 4 * Cout * Cin * 4;
  for (int i = blockIdx.x * 256 + threadIdx.x; i < n; i += gridDim.x * 256) {
    const int tap = i & 3;
    const int ci  = (i >> 2) % Cin;
    const int co  = ((i >> 2) / Cin) % Cout;
    const int ph  = (i >> 2) / (Cin * Cout);
    const int ey = ph >> 1, ex = ph & 1;
    const int ty = tap >> 1, tx = tap & 1;
    const int kidx = (3 - 2 * ty - ey) * 4 + (3 - 2 * tx - ex);
    wbT[i] = f2b(w[((size_t)ci * Cout + co) * 16 + kidx]);
  }
}
// split fp32 -> bf16 hi + bf16 lo (elementwise, layout preserved)
__global__ void k_wsplit(const float* __restrict__ w, ushort_t* __restrict__ wh,
                         ushort_t* __restrict__ wl, int n) {
  for (int i = blockIdx.x * 256 + threadIdx.x; i < n; i += gridDim.x * 256) {
    const float v = w[i];
    const ushort_t h = f2b(v);
    wh[i] = h;
    wl[i] = f2b(v - b2f(h));
  }
}
// codebook [1024,64] -> cbT [64][1024] + cnorm[1024]
__global__ void k_cbt(const float* __restrict__ cb, float* __restrict__ cbT,
                      float* __restrict__ cnorm) {
  const int c = blockIdx.x * 256 + threadIdx.x;
  float s = 0.0f;
  for (int ci = 0; ci < 64; ++ci) {
    const float v = cb[(size_t)c * 64 + ci];
    s += v * v;
    cbT[(size_t)ci * 1024 + c] = v;
  }
  cnorm[c] = s;
}

// ---------------- enc0: conv 4x4 s2 p1, Cin=3, staged, PADDED fp32 out ----------
__global__ __launch_bounds__(256) void k_conv4s2_s3(
    const float* __restrict__ in, const float* __restrict__ wT,
    const float* __restrict__ bias, float* __restrict__ out) {
  const int b   = blockIdx.z;
  const int co0 = blockIdx.y << 4;
  const int oy0 = (blockIdx.x >> 2) << 5;
  const int ox0 = (blockIdx.x & 3) << 5;
  const int tid = threadIdx.x;
  const int ty = tid >> 4, tx = tid & 15;
  __shared__ float tin[3][66][67];
  float acc[4][16];
#pragma unroll
  for (int p = 0; p < 4; ++p)
#pragma unroll
    for (int co = 0; co < 16; ++co) acc[p][co] = 0.0f;

  const int iy0 = (oy0 << 1) - 1, ix0 = (ox0 << 1) - 1;
  for (int c = 0; c < 3; ++c) {
    const float* ip = in + (size_t)(b * 3 + c) * 65536;
    for (int j = tid; j < 66 * 66; j += 256) {
      const int r = j / 66, col = j - r * 66;
      const int iy = iy0 + r, ix = ix0 + col;
      float v = 0.0f;
      if ((unsigned)iy < 256u && (unsigned)ix < 256u) v = ip[iy * 256 + ix];
      tin[c][r][col] = v;
    }
  }
  __syncthreads();
#pragma unroll
  for (int c = 0; c < 3; ++c) {
    const float* wp = wT + (size_t)c * 16 * 64 + co0;
#pragma unroll
    for (int ky = 0; ky < 4; ++ky)
#pragma unroll
      for (int kx = 0; kx < 4; ++kx) {
        const float v0 = tin[c][2 * ty + ky][2 * tx + kx];
        const float v1 = tin[c][2 * ty + ky][2 * tx + 32 + kx];
        const float v2 = tin[c][2 * ty + 32 + ky][2 * tx + kx];
        const float v3 = tin[c][2 * ty + 32 + ky][2 * tx + 32 + kx];
        const float* wk = wp + (ky * 4 + kx) * 64;
#pragma unroll
        for (int co = 0; co < 16; ++co) {
          const float wv = wk[co];
          acc[0][co] = fmaf(v0, wv, acc[0][co]);
          acc[1][co] = fmaf(v1, wv, acc[1][co]);
          acc[2][co] = fmaf(v2, wv, acc[2][co]);
          acc[3][co] = fmaf(v3, wv, acc[3][co]);
        }
      }
  }
#pragma unroll
  for (int co = 0; co < 16; ++co) {
    const float bv = bias[co0 + co];
    float* op = out + (size_t)(b * 64 + co0 + co) * 16900;
    op[(size_t)(oy0 + ty + 1) * 130 + ox0 + tx + 1]        = fmaxf(acc[0][co] + bv, 0.0f);
    op[(size_t)(oy0 + ty + 1) * 130 + ox0 + tx + 17]       = fmaxf(acc[1][co] + bv, 0.0f);
    op[(size_t)(oy0 + ty + 17) * 130 + ox0 + tx + 1]       = fmaxf(acc[2][co] + bv, 0.0f);
    op[(size_t)(oy0 + ty + 17) * 130 + ox0 + tx + 17]      = fmaxf(acc[3][co] + bv, 0.0f);
  }
}

// ---------------- split-bf16 MFMA conv 4x4 s2 p1 (encoder; ~fp32 accuracy) ----------------
// R6-proven structure: fp32 in, f2b staging pack, single chunk/barrier, reg-prefetch.
template <int WSHIFT, int CIN, int COUT, int WP, int INSTRIDE, int WOP, int OUTSTRIDE>
__global__ __launch_bounds__(256) void k_conv4s2_mfma(
    const float* __restrict__ in, const ushort_t* __restrict__ wbh,
    const ushort_t* __restrict__ wbl, const float* __restrict__ bias,
    float* __restrict__ out) {
  constexpr int W = 1 << WSHIFT;
  constexpr int NCH = CIN / 2;  // K-chunk = 32 = 2 ci x 16 taps
  __shared__ __align__(16) short lsAh[64 * 40];
  __shared__ __align__(16) short lsAl[64 * 40];
  __shared__ __align__(16) short lsBh[64 * 40];
  __shared__ __align__(16) short lsBl[64 * 40];

  const int tid = threadIdx.x;
  const int b = blockIdx.z;
  const int co_b0 = blockIdx.y << 6;
  const int pxb0 = blockIdx.x << 6;

  const int spx = tid & 63;
  const int kg  = tid >> 6;
  const int sy = (pxb0 + spx) >> WSHIFT;
  const int sx = (pxb0 + spx) & (W - 1);
  const float* ipa = in + (size_t)(b * CIN + (kg >> 1)) * INSTRIDE
                   + (size_t)(2 * sy + 2 * (kg & 1)) * WP + 2 * sx;
  const ushort_t* wbase_h = wbh + (size_t)(co_b0 + spx) * (CIN * 16) + kg * 8;
  const ushort_t* wbase_l = wbl + (size_t)(co_b0 + spx) * (CIN * 16) + kg * 8;

  const int lane = tid & 63, wid = tid >> 6;
  const int wm = wid & 1, wn = wid >> 1;
  const int arow = lane & 15, ag = lane >> 4;

  f32x4 acc[2][2];
#pragma unroll
  for (int m = 0; m < 2; ++m)
#pragma unroll
    for (int n = 0; n < 2; ++n) acc[m][n] = (f32x4){0.f, 0.f, 0.f, 0.f};

  float pa[8];
  u32x4 pbh, pbl;
  auto loadch = [&](int ch) {
    const float* p = ipa + (size_t)ch * 2 * INSTRIDE;
    pa[0] = p[0];  pa[1] = p[1];      pa[2] = p[2];      pa[3] = p[3];
    pa[4] = p[WP]; pa[5] = p[WP + 1]; pa[6] = p[WP + 2]; pa[7] = p[WP + 3];
    pbh = *(const u32x4*)(wbase_h + (size_t)ch * 32);
    pbl = *(const u32x4*)(wbase_l + (size_t)ch * 32);
  };

  loadch(0);
  for (int ch = 0; ch < NCH; ++ch) {
    __syncthreads();
    u32x4 vh, vl;
#pragma unroll
    for (int j = 0; j < 4; ++j) {
      const ushort_t h0 = f2b(pa[2 * j]);
      const ushort_t h1 = f2b(pa[2 * j + 1]);
      const ushort_t l0 = f2b(pa[2 * j] - b2f(h0));
      const ushort_t l1 = f2b(pa[2 * j + 1] - b2f(h1));
      vh[j] = (uint_t)h0 | ((uint_t)h1 << 16);
      vl[j] = (uint_t)l0 | ((uint_t)l1 << 16);
    }
    *(u32x4*)(&lsAh[spx * 40 + kg * 8]) = vh;
    *(u32x4*)(&lsAl[spx * 40 + kg * 8]) = vl;
    *(u32x4*)(&lsBh[spx * 40 + kg * 8]) = pbh;
    *(u32x4*)(&lsBl[spx * 40 + kg * 8]) = pbl;
    if (ch + 1 < NCH) loadch(ch + 1);
    __syncthreads();
    short8 ah[2], al[2], bh[2], bl[2];
#pragma unroll
    for (int m = 0; m < 2; ++m) {
      ah[m] = *(const short8*)(&lsAh[(wm * 32 + m * 16 + arow) * 40 + ag * 8]);
      al[m] = *(const short8*)(&lsAl[(wm * 32 + m * 16 + arow) * 40 + ag * 8]);
    }
#pragma unroll
    for (int n = 0; n < 2; ++n) {
      bh[n] = *(const short8*)(&lsBh[(wn * 32 + n * 16 + arow) * 40 + ag * 8]);
      bl[n] = *(const short8*)(&lsBl[(wn * 32 + n * 16 + arow) * 40 + ag * 8]);
    }
#pragma unroll
    for (int m = 0; m < 2; ++m)
#pragma unroll
      for (int n = 0; n < 2; ++n) {
        acc[m][n] = __builtin_amdgcn_mfma_f32_16x16x32_bf16(ah[m], bh[n], acc[m][n], 0, 0, 0);
        acc[m][n] = __builtin_amdgcn_mfma_f32_16x16x32_bf16(ah[m], bl[n], acc[m][n], 0, 0, 0);
        acc[m][n] = __builtin_amdgcn_mfma_f32_16x16x32_bf16(al[m], bh[n], acc[m][n], 0, 0, 0);
      }
  }

#pragma unroll
  for (int m = 0; m < 2; ++m)
#pragma unroll
    for (int n = 0; n < 2; ++n) {
      const int col = co_b0 + wn * 32 + n * 16 + arow;
      const float bv = bias[col];
      float* obase = out + (size_t)(b * COUT + col) * OUTSTRIDE;
#pragma unroll
      for (int r = 0; r < 4; ++r) {
        const int pxl = pxb0 + wm * 32 + m * 16 + ag * 4 + r;
        const int yy = pxl >> WSHIFT, xx = pxl & (W - 1);
        obase[(size_t)(yy + 1) * WOP + (xx + 1)] = fmaxf(acc[m][n][r] + bv, 0.0f);
      }
    }
}

// ---------------- conv3x3 p1 (256->64 @32x32), px-parallel (fp32) ----------
__global__ __launch_bounds__(256) void k_conv3x3_px(
    const float* __restrict__ in, const float* __restrict__ wT,
    const float* __restrict__ bias, float* __restrict__ out) {
  const int b   = blockIdx.z;
  const int co0 = blockIdx.y << 4;
  const int px  = blockIdx.x * 256 + threadIdx.x;
  const int y = px >> 5, x = px & 31;
  const float* ip = in + (size_t)b * 256 * 1156 + (size_t)y * 34 + x;
  float acc[16];
#pragma unroll
  for (int co = 0; co < 16; ++co) acc[co] = 0.0f;
  const float* wp = wT + co0;
  for (int ci = 0; ci < 256; ++ci) {
    float v[9];
#pragma unroll
    for (int dy = 0; dy < 3; ++dy)
#pragma unroll
      for (int dx = 0; dx < 3; ++dx) v[dy * 3 + dx] = fmaxf(ip[dy * 34 + dx], 0.0f);
    ip += 1156;
    const float* wk = wp;
#pragma unroll
    for (int t = 0; t < 9; ++t) {
      const float vv = v[t];
#pragma unroll
      for (int co = 0; co < 16; ++co) acc[co] = fmaf(vv, wk[co], acc[co]);
      wk += 64;
    }
    wp += 9 * 64;
  }
  float* op = out + (size_t)(b * 64 + co0) * 1024 + px;
#pragma unroll
  for (int co = 0; co < 16; ++co) op[(size_t)co * 1024] = acc[co] + bias[co0 + co];
}

// ---------------- conv1x1 px-parallel; pad-aware in/out; optional relu / residual ----------
template <int IN_RELU, int HAS_RES, int IN_PAD, int OUT_PAD>
__global__ __launch_bounds__(256) void k_conv1x1_px(
    const float* __restrict__ in, const float* __restrict__ wT,
    const float* __restrict__ bias, const float* __restrict__ res,
    float* __restrict__ out, int Cin, int Cout) {
  const int b   = blockIdx.z;
  const int co0 = blockIdx.y << 4;
  const int px  = blockIdx.x * 256 + threadIdx.x;
  const int ppad = 35 + px + 2 * (px >> 5);
  const int ioff = IN_PAD ? ppad : px;
  const int istr = IN_PAD ? 1156 : 1024;
  const int ooff = OUT_PAD ? ppad : px;
  const int ostr = OUT_PAD ? 1156 : 1024;
  float acc[16];
#pragma unroll
  for (int co = 0; co < 16; ++co) acc[co] = 0.0f;
  const float* ip = in + (size_t)b * Cin * istr + ioff;
  const float* wp = wT + co0;
  for (int ci = 0; ci < Cin; ++ci) {
    float v = *ip;
    if (IN_RELU) v = fmaxf(v, 0.0f);
    ip += istr;
#pragma unroll
    for (int co = 0; co < 16; ++co) acc[co] = fmaf(v, wp[co], acc[co]);
    wp += Cout;
  }
  float* op = out + (size_t)(b * Cout + co0) * ostr + ooff;
  const float* rp = res + (size_t)(b * Cout + co0) * ostr + ooff;
#pragma unroll
  for (int co = 0; co < 16; ++co) {
    float r = acc[co] + bias[co0 + co];
    if (HAS_RES) r += rp[(size_t)co * ostr];
    op[(size_t)co * ostr] = r;
  }
}

// ---------------- MFMA bf16 tconv, reg-prefetch, GRP chunks (K=32*GRP) per barrier ---------
template <int PXB, int COB, int WSHIFT, int CIN, int COUT, int WP,
          int INSTRIDE, int WOP, int OUTSTRIDE, int FINAL, int GRP>
__global__ __launch_bounds__(256) void k_tconv_mfma(
    const float* __restrict__ in, const ushort_t* __restrict__ wbT,
    const float* __restrict__ bias, const float* __restrict__ ow,
    const float* __restrict__ ob, float* __restrict__ out) {
  constexpr int W = 1 << WSHIFT;
  constexpr int NCH = CIN / 8;          // K-chunks of 32 (8 ci x 4 taps)
  constexpr int NGRP = NCH / GRP;
  constexpr int PXSH = (PXB == 64) ? 6 : 7;
  constexpr int COSH = (COB == 64) ? 6 : 5;
  constexpr int NKG = (PXB * 4) / 256;  // 1 or 2
  constexpr int KGSTEP = 256 / PXB;     // 4 or 2
  __shared__ __align__(16) short lsA[GRP][PXB * 40];
  __shared__ __align__(16) short lsB[GRP][COB * 40];
  __shared__ float pxco[FINAL ? PXB : 1][33];

  const int tid = threadIdx.x;
  const int b = blockIdx.z;
  const int phase = blockIdx.y & 3;
  const int ey = phase >> 1, ex = phase & 1;
  const int co_b0 = (blockIdx.y >> 2) * COB;
  const int pxb0 = blockIdx.x * PXB;

  const int spx = tid & (PXB - 1);
  const int kg0 = tid >> PXSH;
  const int sy = (pxb0 + spx) >> WSHIFT;
  const int sx = (pxb0 + spx) & (W - 1);
  const float* ipa = in + (size_t)b * CIN * INSTRIDE + (size_t)(sy + ey) * WP + (sx + ex);
  const int sco = tid & (COB - 1);
  const int skg = tid >> COSH;
  const bool bstage = (tid < COB * 4);
  const ushort_t* wrow = wbT + ((size_t)(phase * COUT + co_b0 + sco) * CIN) * 4;

  const int lane = tid & 63, wid = tid >> 6;
  const int wm = wid % (PXB / 32), wn = wid / (PXB / 32);
  const int arow = lane & 15, ag = lane >> 4;

  f32x4 acc[2][2];
#pragma unroll
  for (int m = 0; m < 2; ++m)
#pragma unroll
    for (int n = 0; n < 2; ++n) acc[m][n] = (f32x4){0.f, 0.f, 0.f, 0.f};

  float pa[GRP][NKG][8];
  u32x4 pb[GRP];
  auto loadgrp = [&](int g) {
#pragma unroll
    for (int c = 0; c < GRP; ++c) {
      const int ch = g * GRP + c;
#pragma unroll
      for (int k = 0; k < NKG; ++k) {
        const float* p = ipa + (size_t)(ch * 8 + (kg0 + k * KGSTEP) * 2) * INSTRIDE;
        const float* q = p + INSTRIDE;
        pa[c][k][0] = p[0]; pa[c][k][1] = p[1]; pa[c][k][2] = p[WP]; pa[c][k][3] = p[WP + 1];
        pa[c][k][4] = q[0]; pa[c][k][5] = q[1]; pa[c][k][6] = q[WP]; pa[c][k][7] = q[WP + 1];
      }
      if (bstage) pb[c] = *(const u32x4*)(wrow + (size_t)ch * 32 + skg * 8);
    }
  };

  loadgrp(0);
  for (int g = 0; g < NGRP; ++g) {
    __syncthreads();
#pragma unroll
    for (int c = 0; c < GRP; ++c) {
#pragma unroll
      for (int k = 0; k < NKG; ++k) {
        u32x4 pk;
        pk[0] = (uint_t)f2b(pa[c][k][0]) | ((uint_t)f2b(pa[c][k][1]) << 16);
        pk[1] = (uint_t)f2b(pa[c][k][2]) | ((uint_t)f2b(pa[c][k][3]) << 16);
        pk[2] = (uint_t)f2b(pa[c][k][4]) | ((uint_t)f2b(pa[c][k][5]) << 16);
        pk[3] = (uint_t)f2b(pa[c][k][6]) | ((uint_t)f2b(pa[c][k][7]) << 16);
        *(u32x4*)(&lsA[c][spx * 40 + (kg0 + k * KGSTEP) * 8]) = pk;
      }
      if (bstage) *(u32x4*)(&lsB[c][sco * 40 + skg * 8]) = pb[c];
    }
    if (g + 1 < NGRP) loadgrp(g + 1);
    __syncthreads();
#pragma unroll
    for (int c = 0; c < GRP; ++c) {
      const short8 a0 = *(const short8*)(&lsA[c][(wm * 32 + arow) * 40 + ag * 8]);
      const short8 a1 = *(const short8*)(&lsA[c][(wm * 32 + 16 + arow) * 40 + ag * 8]);
      const short8 b0 = *(const short8*)(&lsB[c][(wn * 32 + arow) * 40 + ag * 8]);
      const short8 b1 = *(const short8*)(&lsB[c][(wn * 32 + 16 + arow) * 40 + ag * 8]);
      acc[0][0] = __builtin_amdgcn_mfma_f32_16x16x32_bf16(a0, b0, acc[0][0], 0, 0, 0);
      acc[0][1] = __builtin_amdgcn_mfma_f32_16x16x32_bf16(a0, b1, acc[0][1], 0, 0, 0);
      acc[1][0] = __builtin_amdgcn_mfma_f32_16x16x32_bf16(a1, b0, acc[1][0], 0, 0, 0);
      acc[1][1] = __builtin_amdgcn_mfma_f32_16x16x32_bf16(a1, b1, acc[1][1], 0, 0, 0);
    }
  }

  if constexpr (!FINAL) {
#pragma unroll
    for (int m = 0; m < 2; ++m)
#pragma unroll
      for (int n = 0; n < 2; ++n) {
        const int col = co_b0 + wn * 32 + n * 16 + arow;
        const float bv = bias[col];
        float* obase = out + (size_t)(b * COUT + col) * OUTSTRIDE;
#pragma unroll
        for (int r = 0; r < 4; ++r) {
          const int pxl = pxb0 + wm * 32 + m * 16 + ag * 4 + r;
          const int yy = pxl >> WSHIFT, xx = pxl & (W - 1);
          obase[(size_t)(2 * yy + ey + 1) * WOP + (2 * xx + ex + 1)] =
              fmaxf(acc[m][n][r] + bv, 0.0f);
        }
      }
  } else {
#pragma unroll
    for (int m = 0; m < 2; ++m)
#pragma unroll
      for (int n = 0; n < 2; ++n) {
        const int col = wn * 32 + n * 16 + arow;
        const float bv = bias[col];
#pragma unroll
        for (int r = 0; r < 4; ++r) {
          const int pxl = wm * 32 + m * 16 + ag * 4 + r;
          pxco[pxl][col] = fmaxf(acc[m][n][r] + bv, 0.0f);
        }
      }
    __syncthreads();
    if (tid < PXB) {
      const int pxg = pxb0 + tid;
      const int yy = pxg >> WSHIFT, xx = pxg & (W - 1);
      const int oy = 2 * yy + ey, ox = 2 * xx + ex;
      float o0 = ob[0], o1 = ob[1], o2 = ob[2];
#pragma unroll
      for (int co = 0; co < 32; ++co) {
        const float v = pxco[tid][co];
        o0 = fmaf(ow[co], v, o0);
        o1 = fmaf(ow[32 + co], v, o1);
        o2 = fmaf(ow[64 + co], v, o2);
      }
      out[((size_t)(b * 3 + 0) * 256 + oy) * 256 + ox] = o0;
      out[((size_t)(b * 3 + 1) * 256 + oy) * 256 + ox] = o1;
      out[((size_t)(b * 3 + 2) * 256 + oy) * 256 + ox] = o2;
    }
  }
}

// ---------------- VQ (fp32 exact) ----------------
__global__ __launch_bounds__(256) void k_vq(
    const float* __restrict__ zlat, const float* __restrict__ cbT,
    const float* __restrict__ cnorm, const float* __restrict__ cb,
    float* __restrict__ q, float* __restrict__ counts, float* __restrict__ sumsq) {
  const int tid = threadIdx.x;
  const int px0 = blockIdx.x << 4;
  const int b   = px0 >> 10;
  const int pl0 = px0 & 1023;
  __shared__ float zT[64][17];
  __shared__ float rd[16][256];
  __shared__ int   ri[16][256];
  for (int j = tid; j < 1024; j += 256) {
    const int ci = j >> 4, p = j & 15;
    zT[ci][p] = zlat[(size_t)(b * 64 + ci) * 1024 + pl0 + p];
  }
  __syncthreads();
  float dot[4][16];
#pragma unroll
  for (int k = 0; k < 4; ++k)
#pragma unroll
    for (int p = 0; p < 16; ++p) dot[k][p] = 0.0f;
  for (int ci = 0; ci < 64; ++ci) {
    float z[16];
#pragma unroll
    for (int p = 0; p < 16; ++p) z[p] = zT[ci][p];
#pragma unroll
    for (int k = 0; k < 4; ++k) {
      const float cv = cbT[(size_t)ci * 1024 + (k << 8) + tid];
#pragma unroll
      for (int p = 0; p < 16; ++p) dot[k][p] = fmaf(cv, z[p], dot[k][p]);
    }
  }
  float bd[16]; int bi[16];
#pragma unroll
  for (int p = 0; p < 16; ++p) { bd[p] = 3.4e38f; bi[p] = 0; }
#pragma unroll
  for (int k = 0; k < 4; ++k) {
    const int c = (k << 8) + tid;
    const float cn = cnorm[c];
#pragma unroll
    for (int p = 0; p < 16; ++p) {
      const float d = cn - 2.0f * dot[k][p];
      if (d < bd[p]) { bd[p] = d; bi[p] = c; }
    }
  }
#pragma unroll
  for (int p = 0; p < 16; ++p) { rd[p][tid] = bd[p]; ri[p][tid] = bi[p]; }
  __syncthreads();
  for (int s = 128; s >= 1; s >>= 1) {
    if (tid < s) {
#pragma unroll
      for (int p = 0; p < 16; ++p) {
        const float d2 = rd[p][tid + s]; const int i2 = ri[p][tid + s];
        const float d1 = rd[p][tid];     const int i1 = ri[p][tid];
        if (d2 < d1 || (d2 == d1 && i2 < i1)) { rd[p][tid] = d2; ri[p][tid] = i2; }
      }
    }
    __syncthreads();
  }
  if (tid < 16) atomicAdd(&counts[ri[tid][0]], 1.0f);
  const int p    = tid >> 4;
  const int best = ri[p][0];
  const int cb0  = (tid & 15) << 2;
  float ss = 0.0f;
  float* qp = q + (size_t)b * 65536 + pl0 + p;
#pragma unroll
  for (int cc = 0; cc < 4; ++cc) {
    const int ci = cb0 + cc;
    const float qv = cb[(size_t)best * 64 + ci];
    const float zv = zT[ci][p];
    const float df = qv - zv;
    ss += df * df;
    qp[(size_t)ci * 1024] = qv;
  }
#pragma unroll
  for (int o = 32; o > 0; o >>= 1) ss += __shfl_down(ss, o);
  if ((tid & 63) == 0) atomicAdd(sumsq, ss);
}

__global__ void k_final(const float* __restrict__ counts, const float* __restrict__ sumsq,
                        float* __restrict__ out2) {
  const int tid = threadIdx.x;
  float h = 0.0f;
  for (int k = tid; k < 1024; k += 256) {
    const float pr = counts[k] * (1.0f / 32768.0f);
    h -= pr * logf(pr + 1e-10f);
  }
#pragma unroll
  for (int o = 32; o > 0; o >>= 1) h += __shfl_down(h, o);
  __shared__ float hs[4];
  if ((tid & 63) == 0) hs[tid >> 6] = h;
  __syncthreads();
  if (tid == 0) {
    out2[0] = 1.25f * sumsq[0] * (1.0f / 2097152.0f);
    out2[1] = expf(hs[0] + hs[1] + hs[2] + hs[3]);
  }
}

// ---------------- launcher ----------------
extern "C" void kernel_launch(void* const* d_in, const int* in_sizes, int n_in,
                              void* d_out, int out_size, void* d_ws, size_t ws_size,
                              hipStream_t stream) {
  const float* x        = (const float*)d_in[0];
  const float* enc_w0   = (const float*)d_in[1];
  const float* enc_b0   = (const float*)d_in[2];
  const float* enc_w1   = (const float*)d_in[3];
  const float* enc_b1   = (const float*)d_in[4];
  const float* enc_w2   = (const float*)d_in[5];
  const float* enc_b2   = (const float*)d_in[6];
  const float* er0w1    = (const float*)d_in[7];
  const float* er0b1    = (const float*)d_in[8];
  const float* er0w2    = (const float*)d_in[9];
  const float* er0b2    = (const float*)d_in[10];
  const float* er1w1    = (const float*)d_in[11];
  const float* er1b1    = (const float*)d_in[12];
  const float* er1w2    = (const float*)d_in[13];
  const float* er1b2    = (const float*)d_in[14];
  const float* eadj_w   = (const float*)d_in[15];
  const float* eadj_b   = (const float*)d_in[16];
  const float* codebook = (const float*)d_in[17];
  const float* dadj_w   = (const float*)d_in[18];
  const float* dadj_b   = (const float*)d_in[19];
  const float* dr0w1    = (const float*)d_in[20];
  const float* dr0b1    = (const float*)d_in[21];
  const float* dr0w2    = (const float*)d_in[22];
  const float* dr0b2    = (const float*)d_in[23];
  const float* dr1w1    = (const float*)d_in[24];
  const float* dr1b1    = (const float*)d_in[25];
  const float* dr1w2    = (const float*)d_in[26];
  const float* dr1b2    = (const float*)d_in[27];
  const float* tw0      = (const float*)d_in[28];
  const float* tb0      = (const float*)d_in[29];
  const float* tw1      = (const float*)d_in[30];
  const float* tb1      = (const float*)d_in[31];
  const float* tw2      = (const float*)d_in[32];
  const float* tb2      = (const float*)d_in[33];
  const float* out_w    = (const float*)d_in[34];
  const float* out_b    = (const float*)d_in[35];

  float* ws = (float*)d_ws;
  float* A      = ws + A_OFF;
  float* Bb     = ws + B_OFF;
  float* C      = ws + C_OFF;
  float* Dq     = ws + D_OFF;
  float* E      = ws + E_OFF;
  float* Q      = ws + Q_OFF;
  float* cbT    = ws + CBT_OFF;
  float* cnorm  = ws + CNORM_OFF;
  float* counts = ws + COUNTS_OFF;
  float* sumsq  = ws + SUMSQ_OFF;

  size_t o = WT_OFF;
  float* wt_enc0  = ws + o; o += (size_t)3 * 16 * 64;
  float* wt_er0w1 = ws + o; o += (size_t)256 * 9 * 64;
  float* wt_er0w2 = ws + o; o += (size_t)64 * 256;
  float* wt_er1w1 = ws + o; o += (size_t)256 * 9 * 64;
  float* wt_er1w2 = ws + o; o += (size_t)64 * 256;
  float* wt_eadj  = ws + o; o += (size_t)256 * 64;
  float* wt_dadj  = ws + o; o += (size_t)64 * 256;
  float* wt_dr0w1 = ws + o; o += (size_t)256 * 9 * 64;
  float* wt_dr0w2 = ws + o; o += (size_t)64 * 256;
  float* wt_dr1w1 = ws + o; o += (size_t)256 * 9 * 64;
  float* wt_dr1w2 = ws + o; o += (size_t)64 * 256;
  // bf16 tconv weights (CORRECT sizes: u16_count/2 floats)
  ushort_t* wbT0 = (ushort_t*)(ws + o); o += 262144;  // 4*128*256*4 u16 = 524288
  ushort_t* wbT1 = (ushort_t*)(ws + o); o += 65536;   // 4*64*128*4  u16 = 131072
  ushort_t* wbT2 = (ushort_t*)(ws + o); o += 16384;   // 4*32*64*4   u16 = 32768
  // split bf16 encoder conv weights ([co][ci][16] layout preserved)
  ushort_t* wsh1 = (ushort_t*)(ws + o); o += 65536;   // 128*64*16 u16
  ushort_t* wsl1 = (ushort_t*)(ws + o); o += 65536;
  ushort_t* wsh2 = (ushort_t*)(ws + o); o += 262144;  // 256*128*16 u16
  ushort_t* wsl2 = (ushort_t*)(ws + o); o += 262144;

  float* fout = (float*)d_out;

  #define GB(n) (((n) + 255) / 256)
  // zero activation region + smalls (halos + counters)
  hipMemsetAsync(ws, 0, WT_OFF * sizeof(float), stream);

  k_wt_conv<<<GB(3 * 64 * 16), 256, 0, stream>>>(enc_w0, wt_enc0, 3, 64, 16);
  k_wt_conv<<<GB(256 * 64 * 9), 256, 0, stream>>>(er0w1, wt_er0w1, 256, 64, 9);
  k_wt_conv<<<GB(64 * 256), 256, 0, stream>>>(er0w2, wt_er0w2, 64, 256, 1);
  k_wt_conv<<<GB(256 * 64 * 9), 256, 0, stream>>>(er1w1, wt_er1w1, 256, 64, 9);
  k_wt_conv<<<GB(64 * 256), 256, 0, stream>>>(er1w2, wt_er1w2, 64, 256, 1);
  k_wt_conv<<<GB(256 * 64), 256, 0, stream>>>(eadj_w, wt_eadj, 256, 64, 1);
  k_wt_conv<<<GB(64 * 256), 256, 0, stream>>>(dadj_w, wt_dadj, 64, 256, 1);
  k_wt_conv<<<GB(256 * 64 * 9), 256, 0, stream>>>(dr0w1, wt_dr0w1, 256, 64, 9);
  k_wt_conv<<<GB(64 * 256), 256, 0, stream>>>(dr0w2, wt_dr0w2, 64, 256, 1);
  k_wt_conv<<<GB(256 * 64 * 9), 256, 0, stream>>>(dr1w1, wt_dr1w1, 256, 64, 9);
  k_wt_conv<<<GB(64 * 256), 256, 0, stream>>>(dr1w2, wt_dr1w2, 64, 256, 1);
  k_wtb<<<GB(524288), 256, 0, stream>>>(tw0, wbT0, 256, 128);
  k_wtb<<<GB(131072), 256, 0, stream>>>(tw1, wbT1, 128, 64);
  k_wtb<<<GB(32768), 256, 0, stream>>>(tw2, wbT2, 64, 32);
  k_wsplit<<<GB(131072), 256, 0, stream>>>(enc_w1, wsh1, wsl1, 131072);
  k_wsplit<<<GB(524288), 256, 0, stream>>>(enc_w2, wsh2, wsl2, 524288);
  k_cbt<<<4, 256, 0, stream>>>(codebook, cbT, cnorm);

  // ---------- encoder (split-bf16 MFMA ~ fp32 accuracy; protects VQ argmin) ----------
  k_conv4s2_s3<<<dim3(16, 4, 32), 256, 0, stream>>>(x, wt_enc0, enc_b0, A);
  k_conv4s2_mfma<6, 64, 128, 130, 16900, 66, 4356>
      <<<dim3(64, 2, 32), 256, 0, stream>>>(A, wsh1, wsl1, enc_b1, Bb);
  // A now dead -> zero C+D region (halos for enc2/res outputs)
  hipMemsetAsync(ws, 0, (size_t)18939904 * sizeof(float), stream);
  k_conv4s2_mfma<5, 128, 256, 66, 4356, 34, 1156>
      <<<dim3(16, 4, 32), 256, 0, stream>>>(Bb, wsh2, wsl2, enc_b2, C);
  k_conv3x3_px<<<dim3(4, 4, 32), 256, 0, stream>>>(C, wt_er0w1, er0b1, E);
  k_conv1x1_px<1, 1, 0, 1><<<dim3(4, 16, 32), 256, 0, stream>>>(E, wt_er0w2, er0b2, C, Dq, 64, 256);
  k_conv3x3_px<<<dim3(4, 4, 32), 256, 0, stream>>>(Dq, wt_er1w1, er1b1, E);
  k_conv1x1_px<1, 1, 0, 1><<<dim3(4, 16, 32), 256, 0, stream>>>(E, wt_er1w2, er1b2, Dq, C, 64, 256);
  k_conv1x1_px<0, 0, 1, 0><<<dim3(4, 4, 32), 256, 0, stream>>>(C, wt_eadj, eadj_b, nullptr, E, 256, 64);
  // ---------- VQ (fp32 exact) ----------
  k_vq<<<2048, 256, 0, stream>>>(E, cbT, cnorm, codebook, Q, counts, sumsq);
  // ---------- decoder ----------
  k_conv1x1_px<0, 0, 0, 1><<<dim3(4, 16, 32), 256, 0, stream>>>(Q, wt_dadj, dadj_b, nullptr, C, 64, 256);
  k_conv3x3_px<<<dim3(4, 4, 32), 256, 0, stream>>>(C, wt_dr0w1, dr0b1, E);
  k_conv1x1_px<1, 1, 0, 1><<<dim3(4, 16, 32), 256, 0, stream>>>(E, wt_dr0w2, dr0b2, C, Dq, 64, 256);
  k_conv3x3_px<<<dim3(4, 4, 32), 256, 0, stream>>>(Dq, wt_dr1w1, dr1b1, E);
  k_conv1x1_px<1, 1, 0, 1><<<dim3(4, 16, 32), 256, 0, stream>>>(E, wt_dr1w2, dr1b2, Dq, C, 64, 256);
  // MFMA bf16 transposed convs (decoder only; GRP=2 for tconv0/1)
  k_tconv_mfma<64, 64, 5, 256, 128, 34, 1156, 66, 4356, 0, 2>
      <<<dim3(16, 8, 32), 256, 0, stream>>>(C, wbT0, tb0, nullptr, nullptr, Bb);
  // C/D/E/Q dead -> zero A region (halos for tconv1 output)
  hipMemsetAsync(ws, 0, (size_t)34611200 * sizeof(float), stream);
  k_tconv_mfma<64, 64, 6, 128, 64, 66, 4356, 130, 16900, 0, 2>
      <<<dim3(64, 4, 32), 256, 0, stream>>>(Bb, wbT1, tb1, nullptr, nullptr, A);
  k_tconv_mfma<128, 32, 7, 64, 32, 130, 16900, 0, 0, 1, 1>
      <<<dim3(128, 4, 32), 256, 0, stream>>>(A, wbT2, tb2, out_w, out_b, fout);
  k_final<<<1, 256, 0, stream>>>(counts, sumsq, fout + 6291456);
  #undef GB
}

// Round 13
// 1763.639 us; speedup vs baseline: 1.6242x; 1.2868x over previous
//
#include <hip/hip_runtime.h>
#include <math.h>

typedef __attribute__((ext_vector_type(4))) float f32x4;
typedef __attribute__((ext_vector_type(8))) short short8;
typedef __attribute__((ext_vector_type(4))) unsigned int u32x4;
typedef unsigned short ushort_t;
typedef unsigned int uint_t;

// ---------------- workspace layout (float offsets), lifetime-packed, PADDED activations ----
static const size_t A_OFF      = 0;
static const size_t C_OFF      = 0;
static const size_t D_OFF      = 9469952;
static const size_t E_OFF      = 18939904;
static const size_t Q_OFF      = 21037056;
static const size_t B_OFF      = 34611200;
static const size_t CBT_OFF    = 52453376;  // 64*1024
static const size_t CNORM_OFF  = 52518912;  // 1024
static const size_t COUNTS_OFF = 52519936;  // 1024
static const size_t SUMSQ_OFF  = 52520960;  // 1 (+3)
static const size_t WT_OFF     = 52520964;  // transposed weights + bf16/split weights

__device__ __forceinline__ ushort_t f2b(float f) {
  uint_t u = __float_as_uint(f);
  uint_t r = (u + 0x7FFFu + ((u >> 16) & 1u)) >> 16;
  return (ushort_t)r;
}
__device__ __forceinline__ float b2f(ushort_t h) {
  return __uint_as_float(((uint_t)h) << 16);
}

// ---------------- weight prep ----------------
// [Cout,Cin,K] -> [Cin,K,Cout]  (fp32, for fp32 kernels)
__global__ void k_wt_conv(const float* __restrict__ w, float* __restrict__ wT,
                          int Cin, int Cout, int K) {
  const int n = Cin * Cout * K;
  for (int i = blockIdx.x * 256 + threadIdx.x; i < n; i += gridDim.x * 256) {
    const int co = i % Cout;
    const int k  = (i / Cout) % K;
    const int ci = i / (Cout * K);
    wT[i] = w[((size_t)co * Cin + ci) * K + k];
  }
}
// tconv weight [Cin][Cout][16] -> bf16 wbT[phase][co][ci*4+tap]
__global__ void k_wtb(const float* __restrict__ w, ushort_t* __restrict__ wbT,
                      int Cin, int Cout) {
  const int n = 4 * Cout * Cin * 4;
  for (int i = blockIdx.x * 256 + threadIdx.x; i < n; i += gridDim.x * 256) {
    const int tap = i & 3;
    const int ci  = (i >> 2) % Cin;
    const int co  = ((i >> 2) / Cin) % Cout;
    const int ph  = (i >> 2) / (Cin * Cout);
    const int ey = ph >> 1, ex = ph & 1;
    const int ty = tap >> 1, tx = tap & 1;
    const int kidx = (3 - 2 * ty - ey) * 4 + (3 - 2 * tx - ex);
    wbT[i] = f2b(w[((size_t)ci * Cout + co) * 16 + kidx]);
  }
}
// split fp32 -> bf16 hi + bf16 lo (elementwise, layout preserved)
__global__ void k_wsplit(const float* __restrict__ w, ushort_t* __restrict__ wh,
                         ushort_t* __restrict__ wl, int n) {
  for (int i = blockIdx.x * 256 + threadIdx.x; i < n; i += gridDim.x * 256) {
    const float v = w[i];
    const ushort_t h = f2b(v);
    wh[i] = h;
    wl[i] = f2b(v - b2f(h));
  }
}
// conv3x3 weight [64co][256ci][9t] -> split bf16 [9t][64co][256ci]
__global__ void k_wt3split(const float* __restrict__ w, ushort_t* __restrict__ wh,
                           ushort_t* __restrict__ wl) {
  const int n = 9 * 64 * 256;
  for (int i = blockIdx.x * 256 + threadIdx.x; i < n; i += gridDim.x * 256) {
    const int ci = i & 255;
    const int co = (i >> 8) & 63;
    const int t  = i >> 14;
    const float v = w[((size_t)co * 256 + ci) * 9 + t];
    const ushort_t h = f2b(v);
    wh[i] = h;
    wl[i] = f2b(v - b2f(h));
  }
}
// codebook [1024,64] -> cbT [64][1024] + cnorm[1024]
__global__ void k_cbt(const float* __restrict__ cb, float* __restrict__ cbT,
                      float* __restrict__ cnorm) {
  const int c = blockIdx.x * 256 + threadIdx.x;
  float s = 0.0f;
  for (int ci = 0; ci < 64; ++ci) {
    const float v = cb[(size_t)c * 64 + ci];
    s += v * v;
    cbT[(size_t)ci * 1024 + c] = v;
  }
  cnorm[c] = s;
}

// ---------------- enc0: conv 4x4 s2 p1, Cin=3, staged, PADDED fp32 out ----------
__global__ __launch_bounds__(256) void k_conv4s2_s3(
    const float* __restrict__ in, const float* __restrict__ wT,
    const float* __restrict__ bias, float* __restrict__ out) {
  const int b   = blockIdx.z;
  const int co0 = blockIdx.y << 4;
  const int oy0 = (blockIdx.x >> 2) << 5;
  const int ox0 = (blockIdx.x & 3) << 5;
  const int tid = threadIdx.x;
  const int ty = tid >> 4, tx = tid & 15;
  __shared__ float tin[3][66][67];
  float acc[4][16];
#pragma unroll
  for (int p = 0; p < 4; ++p)
#pragma unroll
    for (int co = 0; co < 16; ++co) acc[p][co] = 0.0f;

  const int iy0 = (oy0 << 1) - 1, ix0 = (ox0 << 1) - 1;
  for (int c = 0; c < 3; ++c) {
    const float* ip = in + (size_t)(b * 3 + c) * 65536;
    for (int j = tid; j < 66 * 66; j += 256) {
      const int r = j / 66, col = j - r * 66;
      const int iy = iy0 + r, ix = ix0 + col;
      float v = 0.0f;
      if ((unsigned)iy < 256u && (unsigned)ix < 256u) v = ip[iy * 256 + ix];
      tin[c][r][col] = v;
    }
  }
  __syncthreads();
#pragma unroll
  for (int c = 0; c < 3; ++c) {
    const float* wp = wT + (size_t)c * 16 * 64 + co0;
#pragma unroll
    for (int ky = 0; ky < 4; ++ky)
#pragma unroll
      for (int kx = 0; kx < 4; ++kx) {
        const float v0 = tin[c][2 * ty + ky][2 * tx + kx];
        const float v1 = tin[c][2 * ty + ky][2 * tx + 32 + kx];
        const float v2 = tin[c][2 * ty + 32 + ky][2 * tx + kx];
        const float v3 = tin[c][2 * ty + 32 + ky][2 * tx + 32 + kx];
        const float* wk = wp + (ky * 4 + kx) * 64;
#pragma unroll
        for (int co = 0; co < 16; ++co) {
          const float wv = wk[co];
          acc[0][co] = fmaf(v0, wv, acc[0][co]);
          acc[1][co] = fmaf(v1, wv, acc[1][co]);
          acc[2][co] = fmaf(v2, wv, acc[2][co]);
          acc[3][co] = fmaf(v3, wv, acc[3][co]);
        }
      }
  }
#pragma unroll
  for (int co = 0; co < 16; ++co) {
    const float bv = bias[co0 + co];
    float* op = out + (size_t)(b * 64 + co0 + co) * 16900;
    op[(size_t)(oy0 + ty + 1) * 130 + ox0 + tx + 1]        = fmaxf(acc[0][co] + bv, 0.0f);
    op[(size_t)(oy0 + ty + 1) * 130 + ox0 + tx + 17]       = fmaxf(acc[1][co] + bv, 0.0f);
    op[(size_t)(oy0 + ty + 17) * 130 + ox0 + tx + 1]       = fmaxf(acc[2][co] + bv, 0.0f);
    op[(size_t)(oy0 + ty + 17) * 130 + ox0 + tx + 17]      = fmaxf(acc[3][co] + bv, 0.0f);
  }
}

// ---------------- split-bf16 MFMA conv 4x4 s2 p1 (encoder; ~fp32 accuracy) ----------------
template <int WSHIFT, int CIN, int COUT, int WP, int INSTRIDE, int WOP, int OUTSTRIDE>
__global__ __launch_bounds__(256) void k_conv4s2_mfma(
    const float* __restrict__ in, const ushort_t* __restrict__ wbh,
    const ushort_t* __restrict__ wbl, const float* __restrict__ bias,
    float* __restrict__ out) {
  constexpr int W = 1 << WSHIFT;
  constexpr int NCH = CIN / 2;  // K-chunk = 32 = 2 ci x 16 taps
  __shared__ __align__(16) short lsAh[64 * 40];
  __shared__ __align__(16) short lsAl[64 * 40];
  __shared__ __align__(16) short lsBh[64 * 40];
  __shared__ __align__(16) short lsBl[64 * 40];

  const int tid = threadIdx.x;
  const int b = blockIdx.z;
  const int co_b0 = blockIdx.y << 6;
  const int pxb0 = blockIdx.x << 6;

  const int spx = tid & 63;
  const int kg  = tid >> 6;
  const int sy = (pxb0 + spx) >> WSHIFT;
  const int sx = (pxb0 + spx) & (W - 1);
  const float* ipa = in + (size_t)(b * CIN + (kg >> 1)) * INSTRIDE
                   + (size_t)(2 * sy + 2 * (kg & 1)) * WP + 2 * sx;
  const ushort_t* wbase_h = wbh + (size_t)(co_b0 + spx) * (CIN * 16) + kg * 8;
  const ushort_t* wbase_l = wbl + (size_t)(co_b0 + spx) * (CIN * 16) + kg * 8;

  const int lane = tid & 63, wid = tid >> 6;
  const int wm = wid & 1, wn = wid >> 1;
  const int arow = lane & 15, ag = lane >> 4;

  f32x4 acc[2][2];
#pragma unroll
  for (int m = 0; m < 2; ++m)
#pragma unroll
    for (int n = 0; n < 2; ++n) acc[m][n] = (f32x4){0.f, 0.f, 0.f, 0.f};

  float pa[8];
  u32x4 pbh, pbl;
  auto loadch = [&](int ch) {
    const float* p = ipa + (size_t)ch * 2 * INSTRIDE;
    pa[0] = p[0];  pa[1] = p[1];      pa[2] = p[2];      pa[3] = p[3];
    pa[4] = p[WP]; pa[5] = p[WP + 1]; pa[6] = p[WP + 2]; pa[7] = p[WP + 3];
    pbh = *(const u32x4*)(wbase_h + (size_t)ch * 32);
    pbl = *(const u32x4*)(wbase_l + (size_t)ch * 32);
  };

  loadch(0);
  for (int ch = 0; ch < NCH; ++ch) {
    __syncthreads();
    u32x4 vh, vl;
#pragma unroll
    for (int j = 0; j < 4; ++j) {
      const ushort_t h0 = f2b(pa[2 * j]);
      const ushort_t h1 = f2b(pa[2 * j + 1]);
      const ushort_t l0 = f2b(pa[2 * j] - b2f(h0));
      const ushort_t l1 = f2b(pa[2 * j + 1] - b2f(h1));
      vh[j] = (uint_t)h0 | ((uint_t)h1 << 16);
      vl[j] = (uint_t)l0 | ((uint_t)l1 << 16);
    }
    *(u32x4*)(&lsAh[spx * 40 + kg * 8]) = vh;
    *(u32x4*)(&lsAl[spx * 40 + kg * 8]) = vl;
    *(u32x4*)(&lsBh[spx * 40 + kg * 8]) = pbh;
    *(u32x4*)(&lsBl[spx * 40 + kg * 8]) = pbl;
    if (ch + 1 < NCH) loadch(ch + 1);
    __syncthreads();
    short8 ah[2], al[2], bh[2], bl[2];
#pragma unroll
    for (int m = 0; m < 2; ++m) {
      ah[m] = *(const short8*)(&lsAh[(wm * 32 + m * 16 + arow) * 40 + ag * 8]);
      al[m] = *(const short8*)(&lsAl[(wm * 32 + m * 16 + arow) * 40 + ag * 8]);
    }
#pragma unroll
    for (int n = 0; n < 2; ++n) {
      bh[n] = *(const short8*)(&lsBh[(wn * 32 + n * 16 + arow) * 40 + ag * 8]);
      bl[n] = *(const short8*)(&lsBl[(wn * 32 + n * 16 + arow) * 40 + ag * 8]);
    }
#pragma unroll
    for (int m = 0; m < 2; ++m)
#pragma unroll
      for (int n = 0; n < 2; ++n) {
        acc[m][n] = __builtin_amdgcn_mfma_f32_16x16x32_bf16(ah[m], bh[n], acc[m][n], 0, 0, 0);
        acc[m][n] = __builtin_amdgcn_mfma_f32_16x16x32_bf16(ah[m], bl[n], acc[m][n], 0, 0, 0);
        acc[m][n] = __builtin_amdgcn_mfma_f32_16x16x32_bf16(al[m], bh[n], acc[m][n], 0, 0, 0);
      }
  }

#pragma unroll
  for (int m = 0; m < 2; ++m)
#pragma unroll
    for (int n = 0; n < 2; ++n) {
      const int col = co_b0 + wn * 32 + n * 16 + arow;
      const float bv = bias[col];
      float* obase = out + (size_t)(b * COUT + col) * OUTSTRIDE;
#pragma unroll
      for (int r = 0; r < 4; ++r) {
        const int pxl = pxb0 + wm * 32 + m * 16 + ag * 4 + r;
        const int yy = pxl >> WSHIFT, xx = pxl & (W - 1);
        obase[(size_t)(yy + 1) * WOP + (xx + 1)] = fmaxf(acc[m][n][r] + bv, 0.0f);
      }
    }
}

// ---------------- split-bf16 MFMA conv3x3 p1 (256->64 @32x32), tap-decomposed ----------
// M=1024px, N=64co, K=256ci per tap, 9 taps. 512 threads: tid<256 stage A, tid>=256 stage B.
// Relu on input at staging. Output dense [64][1024], pre-relu (consumer applies relu).
__global__ __launch_bounds__(512) void k_conv3x3_mfma(
    const float* __restrict__ in, const ushort_t* __restrict__ w3h,
    const ushort_t* __restrict__ w3l, const float* __restrict__ bias,
    float* __restrict__ out) {
  __shared__ __align__(16) short lsAh[64 * 40];
  __shared__ __align__(16) short lsAl[64 * 40];
  __shared__ __align__(16) short lsBh[64 * 40];
  __shared__ __align__(16) short lsBl[64 * 40];

  const int tid = threadIdx.x;
  const int b = blockIdx.z;
  const int pxb0 = blockIdx.x << 6;
  const bool isA = tid < 256;
  const int sidx = tid & 63;        // spx or sco
  const int skg  = (tid >> 6) & 3;  // k-group 0..3

  const int py = (pxb0 + sidx) >> 5;
  const int pxx = (pxb0 + sidx) & 31;
  const float* ipa = in + (size_t)b * 256 * 1156 + (size_t)(py)*34 + pxx;  // +dy*34+dx+ch*1156

  const int lane = tid & 63, wid = tid >> 6;
  const int wm = wid & 1, wn = wid >> 1;  // wm 0..1 (px half), wn 0..3 (16-co quarter)
  const int arow = lane & 15, ag = lane >> 4;

  f32x4 acc[2];
  acc[0] = (f32x4){0.f, 0.f, 0.f, 0.f};
  acc[1] = (f32x4){0.f, 0.f, 0.f, 0.f};

  float pa[8];
  u32x4 pbh, pbl;
  auto loadit = [&](int it) {
    const int t = it >> 3, ck = it & 7;
    if (isA) {
      const int dy = t / 3, dx = t - 3 * (t / 3);
      const float* p = ipa + (size_t)(ck * 32 + skg * 8) * 1156 + dy * 34 + dx;
#pragma unroll
      for (int j = 0; j < 8; ++j) pa[j] = p[(size_t)j * 1156];
    } else {
      const ushort_t* ph = w3h + ((size_t)(t * 64 + sidx) << 8) + ck * 32 + skg * 8;
      const ushort_t* pl = w3l + ((size_t)(t * 64 + sidx) << 8) + ck * 32 + skg * 8;
      pbh = *(const u32x4*)ph;
      pbl = *(const u32x4*)pl;
    }
  };

  loadit(0);
  for (int it = 0; it < 72; ++it) {
    __syncthreads();
    if (isA) {
      u32x4 vh, vl;
#pragma unroll
      for (int j = 0; j < 4; ++j) {
        const float v0 = fmaxf(pa[2 * j], 0.0f);
        const float v1 = fmaxf(pa[2 * j + 1], 0.0f);
        const ushort_t h0 = f2b(v0);
        const ushort_t h1 = f2b(v1);
        const ushort_t l0 = f2b(v0 - b2f(h0));
        const ushort_t l1 = f2b(v1 - b2f(h1));
        vh[j] = (uint_t)h0 | ((uint_t)h1 << 16);
        vl[j] = (uint_t)l0 | ((uint_t)l1 << 16);
      }
      *(u32x4*)(&lsAh[sidx * 40 + skg * 8]) = vh;
      *(u32x4*)(&lsAl[sidx * 40 + skg * 8]) = vl;
    } else {
      *(u32x4*)(&lsBh[sidx * 40 + skg * 8]) = pbh;
      *(u32x4*)(&lsBl[sidx * 40 + skg * 8]) = pbl;
    }
    if (it + 1 < 72) loadit(it + 1);
    __syncthreads();
    short8 ah[2], al[2];
#pragma unroll
    for (int m = 0; m < 2; ++m) {
      ah[m] = *(const short8*)(&lsAh[(wm * 32 + m * 16 + arow) * 40 + ag * 8]);
      al[m] = *(const short8*)(&lsAl[(wm * 32 + m * 16 + arow) * 40 + ag * 8]);
    }
    const short8 bh = *(const short8*)(&lsBh[(wn * 16 + arow) * 40 + ag * 8]);
    const short8 bl = *(const short8*)(&lsBl[(wn * 16 + arow) * 40 + ag * 8]);
#pragma unroll
    for (int m = 0; m < 2; ++m) {
      acc[m] = __builtin_amdgcn_mfma_f32_16x16x32_bf16(ah[m], bh, acc[m], 0, 0, 0);
      acc[m] = __builtin_amdgcn_mfma_f32_16x16x32_bf16(ah[m], bl, acc[m], 0, 0, 0);
      acc[m] = __builtin_amdgcn_mfma_f32_16x16x32_bf16(al[m], bh, acc[m], 0, 0, 0);
    }
  }

  const int col = wn * 16 + arow;
  const float bv = bias[col];
  float* obase = out + (size_t)(b * 64 + col) * 1024;
#pragma unroll
  for (int m = 0; m < 2; ++m)
#pragma unroll
    for (int r = 0; r < 4; ++r) {
      const int pxl = pxb0 + wm * 32 + m * 16 + ag * 4 + r;
      obase[pxl] = acc[m][r] + bv;
    }
}

// ---------------- conv1x1 px-parallel; pad-aware in/out; optional relu / residual ----------
template <int IN_RELU, int HAS_RES, int IN_PAD, int OUT_PAD>
__global__ __launch_bounds__(256) void k_conv1x1_px(
    const float* __restrict__ in, const float* __restrict__ wT,
    const float* __restrict__ bias, const float* __restrict__ res,
    float* __restrict__ out, int Cin, int Cout) {
  const int b   = blockIdx.z;
  const int co0 = blockIdx.y << 4;
  const int px  = blockIdx.x * 256 + threadIdx.x;
  const int ppad = 35 + px + 2 * (px >> 5);
  const int ioff = IN_PAD ? ppad : px;
  const int istr = IN_PAD ? 1156 : 1024;
  const int ooff = OUT_PAD ? ppad : px;
  const int ostr = OUT_PAD ? 1156 : 1024;
  float acc[16];
#pragma unroll
  for (int co = 0; co < 16; ++co) acc[co] = 0.0f;
  const float* ip = in + (size_t)b * Cin * istr + ioff;
  const float* wp = wT + co0;
  for (int ci = 0; ci < Cin; ++ci) {
    float v = *ip;
    if (IN_RELU) v = fmaxf(v, 0.0f);
    ip += istr;
#pragma unroll
    for (int co = 0; co < 16; ++co) acc[co] = fmaf(v, wp[co], acc[co]);
    wp += Cout;
  }
  float* op = out + (size_t)(b * Cout + co0) * ostr + ooff;
  const float* rp = res + (size_t)(b * Cout + co0) * ostr + ooff;
#pragma unroll
  for (int co = 0; co < 16; ++co) {
    float r = acc[co] + bias[co0 + co];
    if (HAS_RES) r += rp[(size_t)co * ostr];
    op[(size_t)co * ostr] = r;
  }
}

// ---------------- MFMA bf16 tconv, reg-prefetch, GRP chunks (K=32*GRP) per barrier ---------
template <int PXB, int COB, int WSHIFT, int CIN, int COUT, int WP,
          int INSTRIDE, int WOP, int OUTSTRIDE, int FINAL, int GRP>
__global__ __launch_bounds__(256) void k_tconv_mfma(
    const float* __restrict__ in, const ushort_t* __restrict__ wbT,
    const float* __restrict__ bias, const float* __restrict__ ow,
    const float* __restrict__ ob, float* __restrict__ out) {
  constexpr int W = 1 << WSHIFT;
  constexpr int NCH = CIN / 8;          // K-chunks of 32 (8 ci x 4 taps)
  constexpr int NGRP = NCH / GRP;
  constexpr int PXSH = (PXB == 64) ? 6 : 7;
  constexpr int COSH = (COB == 64) ? 6 : 5;
  constexpr int NKG = (PXB * 4) / 256;  // 1 or 2
  constexpr int KGSTEP = 256 / PXB;     // 4 or 2
  __shared__ __align__(16) short lsA[GRP][PXB * 40];
  __shared__ __align__(16) short lsB[GRP][COB * 40];
  __shared__ float pxco[FINAL ? PXB : 1][33];

  const int tid = threadIdx.x;
  const int b = blockIdx.z;
  const int phase = blockIdx.y & 3;
  const int ey = phase >> 1, ex = phase & 1;
  const int co_b0 = (blockIdx.y >> 2) * COB;
  const int pxb0 = blockIdx.x * PXB;

  const int spx = tid & (PXB - 1);
  const int kg0 = tid >> PXSH;
  const int sy = (pxb0 + spx) >> WSHIFT;
  const int sx = (pxb0 + spx) & (W - 1);
  const float* ipa = in + (size_t)b * CIN * INSTRIDE + (size_t)(sy + ey) * WP + (sx + ex);
  const int sco = tid & (COB - 1);
  const int skg = tid >> COSH;
  const bool bstage = (tid < COB * 4);
  const ushort_t* wrow = wbT + ((size_t)(phase * COUT + co_b0 + sco) * CIN) * 4;

  const int lane = tid & 63, wid = tid >> 6;
  const int wm = wid % (PXB / 32), wn = wid / (PXB / 32);
  const int arow = lane & 15, ag = lane >> 4;

  f32x4 acc[2][2];
#pragma unroll
  for (int m = 0; m < 2; ++m)
#pragma unroll
    for (int n = 0; n < 2; ++n) acc[m][n] = (f32x4){0.f, 0.f, 0.f, 0.f};

  float pa[GRP][NKG][8];
  u32x4 pb[GRP];
  auto loadgrp = [&](int g) {
#pragma unroll
    for (int c = 0; c < GRP; ++c) {
      const int ch = g * GRP + c;
#pragma unroll
      for (int k = 0; k < NKG; ++k) {
        const float* p = ipa + (size_t)(ch * 8 + (kg0 + k * KGSTEP) * 2) * INSTRIDE;
        const float* q = p + INSTRIDE;
        pa[c][k][0] = p[0]; pa[c][k][1] = p[1]; pa[c][k][2] = p[WP]; pa[c][k][3] = p[WP + 1];
        pa[c][k][4] = q[0]; pa[c][k][5] = q[1]; pa[c][k][6] = q[WP]; pa[c][k][7] = q[WP + 1];
      }
      if (bstage) pb[c] = *(const u32x4*)(wrow + (size_t)ch * 32 + skg * 8);
    }
  };

  loadgrp(0);
  for (int g = 0; g < NGRP; ++g) {
    __syncthreads();
#pragma unroll
    for (int c = 0; c < GRP; ++c) {
#pragma unroll
      for (int k = 0; k < NKG; ++k) {
        u32x4 pk;
        pk[0] = (uint_t)f2b(pa[c][k][0]) | ((uint_t)f2b(pa[c][k][1]) << 16);
        pk[1] = (uint_t)f2b(pa[c][k][2]) | ((uint_t)f2b(pa[c][k][3]) << 16);
        pk[2] = (uint_t)f2b(pa[c][k][4]) | ((uint_t)f2b(pa[c][k][5]) << 16);
        pk[3] = (uint_t)f2b(pa[c][k][6]) | ((uint_t)f2b(pa[c][k][7]) << 16);
        *(u32x4*)(&lsA[c][spx * 40 + (kg0 + k * KGSTEP) * 8]) = pk;
      }
      if (bstage) *(u32x4*)(&lsB[c][sco * 40 + skg * 8]) = pb[c];
    }
    if (g + 1 < NGRP) loadgrp(g + 1);
    __syncthreads();
#pragma unroll
    for (int c = 0; c < GRP; ++c) {
      const short8 a0 = *(const short8*)(&lsA[c][(wm * 32 + arow) * 40 + ag * 8]);
      const short8 a1 = *(const short8*)(&lsA[c][(wm * 32 + 16 + arow) * 40 + ag * 8]);
      const short8 b0 = *(const short8*)(&lsB[c][(wn * 32 + arow) * 40 + ag * 8]);
      const short8 b1 = *(const short8*)(&lsB[c][(wn * 32 + 16 + arow) * 40 + ag * 8]);
      acc[0][0] = __builtin_amdgcn_mfma_f32_16x16x32_bf16(a0, b0, acc[0][0], 0, 0, 0);
      acc[0][1] = __builtin_amdgcn_mfma_f32_16x16x32_bf16(a0, b1, acc[0][1], 0, 0, 0);
      acc[1][0] = __builtin_amdgcn_mfma_f32_16x16x32_bf16(a1, b0, acc[1][0], 0, 0, 0);
      acc[1][1] = __builtin_amdgcn_mfma_f32_16x16x32_bf16(a1, b1, acc[1][1], 0, 0, 0);
    }
  }

  if constexpr (!FINAL) {
#pragma unroll
    for (int m = 0; m < 2; ++m)
#pragma unroll
      for (int n = 0; n < 2; ++n) {
        const int col = co_b0 + wn * 32 + n * 16 + arow;
        const float bv = bias[col];
        float* obase = out + (size_t)(b * COUT + col) * OUTSTRIDE;
#pragma unroll
        for (int r = 0; r < 4; ++r) {
          const int pxl = pxb0 + wm * 32 + m * 16 + ag * 4 + r;
          const int yy = pxl >> WSHIFT, xx = pxl & (W - 1);
          obase[(size_t)(2 * yy + ey + 1) * WOP + (2 * xx + ex + 1)] =
              fmaxf(acc[m][n][r] + bv, 0.0f);
        }
      }
  } else {
#pragma unroll
    for (int m = 0; m < 2; ++m)
#pragma unroll
      for (int n = 0; n < 2; ++n) {
        const int col = wn * 32 + n * 16 + arow;
        const float bv = bias[col];
#pragma unroll
        for (int r = 0; r < 4; ++r) {
          const int pxl = wm * 32 + m * 16 + ag * 4 + r;
          pxco[pxl][col] = fmaxf(acc[m][n][r] + bv, 0.0f);
        }
      }
    __syncthreads();
    if (tid < PXB) {
      const int pxg = pxb0 + tid;
      const int yy = pxg >> WSHIFT, xx = pxg & (W - 1);
      const int oy = 2 * yy + ey, ox = 2 * xx + ex;
      float o0 = ob[0], o1 = ob[1], o2 = ob[2];
#pragma unroll
      for (int co = 0; co < 32; ++co) {
        const float v = pxco[tid][co];
        o0 = fmaf(ow[co], v, o0);
        o1 = fmaf(ow[32 + co], v, o1);
        o2 = fmaf(ow[64 + co], v, o2);
      }
      out[((size_t)(b * 3 + 0) * 256 + oy) * 256 + ox] = o0;
      out[((size_t)(b * 3 + 1) * 256 + oy) * 256 + ox] = o1;
      out[((size_t)(b * 3 + 2) * 256 + oy) * 256 + ox] = o2;
    }
  }
}

// ---------------- VQ (fp32 exact) ----------------
__global__ __launch_bounds__(256) void k_vq(
    const float* __restrict__ zlat, const float* __restrict__ cbT,
    const float* __restrict__ cnorm, const float* __restrict__ cb,
    float* __restrict__ q, float* __restrict__ counts, float* __restrict__ sumsq) {
  const int tid = threadIdx.x;
  const int px0 = blockIdx.x << 4;
  const int b   = px0 >> 10;
  const int pl0 = px0 & 1023;
  __shared__ float zT[64][17];
  __shared__ float rd[16][256];
  __shared__ int   ri[16][256];
  for (int j = tid; j < 1024; j += 256) {
    const int ci = j >> 4, p = j & 15;
    zT[ci][p] = zlat[(size_t)(b * 64 + ci) * 1024 + pl0 + p];
  }
  __syncthreads();
  float dot[4][16];
#pragma unroll
  for (int k = 0; k < 4; ++k)
#pragma unroll
    for (int p = 0; p < 16; ++p) dot[k][p] = 0.0f;
  for (int ci = 0; ci < 64; ++ci) {
    float z[16];
#pragma unroll
    for (int p = 0; p < 16; ++p) z[p] = zT[ci][p];
#pragma unroll
    for (int k = 0; k < 4; ++k) {
      const float cv = cbT[(size_t)ci * 1024 + (k << 8) + tid];
#pragma unroll
      for (int p = 0; p < 16; ++p) dot[k][p] = fmaf(cv, z[p], dot[k][p]);
    }
  }
  float bd[16]; int bi[16];
#pragma unroll
  for (int p = 0; p < 16; ++p) { bd[p] = 3.4e38f; bi[p] = 0; }
#pragma unroll
  for (int k = 0; k < 4; ++k) {
    const int c = (k << 8) + tid;
    const float cn = cnorm[c];
#pragma unroll
    for (int p = 0; p < 16; ++p) {
      const float d = cn - 2.0f * dot[k][p];
      if (d < bd[p]) { bd[p] = d; bi[p] = c; }
    }
  }
#pragma unroll
  for (int p = 0; p < 16; ++p) { rd[p][tid] = bd[p]; ri[p][tid] = bi[p]; }
  __syncthreads();
  for (int s = 128; s >= 1; s >>= 1) {
    if (tid < s) {
#pragma unroll
      for (int p = 0; p < 16; ++p) {
        const float d2 = rd[p][tid + s]; const int i2 = ri[p][tid + s];
        const float d1 = rd[p][tid];     const int i1 = ri[p][tid];
        if (d2 < d1 || (d2 == d1 && i2 < i1)) { rd[p][tid] = d2; ri[p][tid] = i2; }
      }
    }
    __syncthreads();
  }
  if (tid < 16) atomicAdd(&counts[ri[tid][0]], 1.0f);
  const int p    = tid >> 4;
  const int best = ri[p][0];
  const int cb0  = (tid & 15) << 2;
  float ss = 0.0f;
  float* qp = q + (size_t)b * 65536 + pl0 + p;
#pragma unroll
  for (int cc = 0; cc < 4; ++cc) {
    const int ci = cb0 + cc;
    const float qv = cb[(size_t)best * 64 + ci];
    const float zv = zT[ci][p];
    const float df = qv - zv;
    ss += df * df;
    qp[(size_t)ci * 1024] = qv;
  }
#pragma unroll
  for (int o = 32; o > 0; o >>= 1) ss += __shfl_down(ss, o);
  if ((tid & 63) == 0) atomicAdd(sumsq, ss);
}

__global__ void k_final(const float* __restrict__ counts, const float* __restrict__ sumsq,
                        float* __restrict__ out2) {
  const int tid = threadIdx.x;
  float h = 0.0f;
  for (int k = tid; k < 1024; k += 256) {
    const float pr = counts[k] * (1.0f / 32768.0f);
    h -= pr * logf(pr + 1e-10f);
  }
#pragma unroll
  for (int o = 32; o > 0; o >>= 1) h += __shfl_down(h, o);
  __shared__ float hs[4];
  if ((tid & 63) == 0) hs[tid >> 6] = h;
  __syncthreads();
  if (tid == 0) {
    out2[0] = 1.25f * sumsq[0] * (1.0f / 2097152.0f);
    out2[1] = expf(hs[0] + hs[1] + hs[2] + hs[3]);
  }
}

// ---------------- launcher ----------------
extern "C" void kernel_launch(void* const* d_in, const int* in_sizes, int n_in,
                              void* d_out, int out_size, void* d_ws, size_t ws_size,
                              hipStream_t stream) {
  const float* x        = (const float*)d_in[0];
  const float* enc_w0   = (const float*)d_in[1];
  const float* enc_b0   = (const float*)d_in[2];
  const float* enc_w1   = (const float*)d_in[3];
  const float* enc_b1   = (const float*)d_in[4];
  const float* enc_w2   = (const float*)d_in[5];
  const float* enc_b2   = (const float*)d_in[6];
  const float* er0w1    = (const float*)d_in[7];
  const float* er0b1    = (const float*)d_in[8];
  const float* er0w2    = (const float*)d_in[9];
  const float* er0b2    = (const float*)d_in[10];
  const float* er1w1    = (const float*)d_in[11];
  const float* er1b1    = (const float*)d_in[12];
  const float* er1w2    = (const float*)d_in[13];
  const float* er1b2    = (const float*)d_in[14];
  const float* eadj_w   = (const float*)d_in[15];
  const float* eadj_b   = (const float*)d_in[16];
  const float* codebook = (const float*)d_in[17];
  const float* dadj_w   = (const float*)d_in[18];
  const float* dadj_b   = (const float*)d_in[19];
  const float* dr0w1    = (const float*)d_in[20];
  const float* dr0b1    = (const float*)d_in[21];
  const float* dr0w2    = (const float*)d_in[22];
  const float* dr0b2    = (const float*)d_in[23];
  const float* dr1w1    = (const float*)d_in[24];
  const float* dr1b1    = (const float*)d_in[25];
  const float* dr1w2    = (const float*)d_in[26];
  const float* dr1b2    = (const float*)d_in[27];
  const float* tw0      = (const float*)d_in[28];
  const float* tb0      = (const float*)d_in[29];
  const float* tw1      = (const float*)d_in[30];
  const float* tb1      = (const float*)d_in[31];
  const float* tw2      = (const float*)d_in[32];
  const float* tb2      = (const float*)d_in[33];
  const float* out_w    = (const float*)d_in[34];
  const float* out_b    = (const float*)d_in[35];

  float* ws = (float*)d_ws;
  float* A      = ws + A_OFF;
  float* Bb     = ws + B_OFF;
  float* C      = ws + C_OFF;
  float* Dq     = ws + D_OFF;
  float* E      = ws + E_OFF;
  float* Q      = ws + Q_OFF;
  float* cbT    = ws + CBT_OFF;
  float* cnorm  = ws + CNORM_OFF;
  float* counts = ws + COUNTS_OFF;
  float* sumsq  = ws + SUMSQ_OFF;

  size_t o = WT_OFF;
  float* wt_enc0  = ws + o; o += (size_t)3 * 16 * 64;
  float* wt_er0w2 = ws + o; o += (size_t)64 * 256;
  float* wt_er1w2 = ws + o; o += (size_t)64 * 256;
  float* wt_eadj  = ws + o; o += (size_t)256 * 64;
  float* wt_dadj  = ws + o; o += (size_t)64 * 256;
  float* wt_dr0w2 = ws + o; o += (size_t)64 * 256;
  float* wt_dr1w2 = ws + o; o += (size_t)64 * 256;
  // bf16 tconv weights
  ushort_t* wbT0 = (ushort_t*)(ws + o); o += 262144;  // 4*128*256*4 u16 = 524288
  ushort_t* wbT1 = (ushort_t*)(ws + o); o += 65536;   // 4*64*128*4  u16 = 131072
  ushort_t* wbT2 = (ushort_t*)(ws + o); o += 16384;   // 4*32*64*4   u16 = 32768
  // split bf16 encoder conv weights ([co][ci][16] layout preserved)
  ushort_t* wsh1 = (ushort_t*)(ws + o); o += 65536;   // 128*64*16 u16
  ushort_t* wsl1 = (ushort_t*)(ws + o); o += 65536;
  ushort_t* wsh2 = (ushort_t*)(ws + o); o += 262144;  // 256*128*16 u16
  ushort_t* wsl2 = (ushort_t*)(ws + o); o += 262144;
  // split bf16 conv3x3 weights [9t][64co][256ci], 147456 u16 each
  ushort_t* w3h_er0 = (ushort_t*)(ws + o); o += 73728;
  ushort_t* w3l_er0 = (ushort_t*)(ws + o); o += 73728;
  ushort_t* w3h_er1 = (ushort_t*)(ws + o); o += 73728;
  ushort_t* w3l_er1 = (ushort_t*)(ws + o); o += 73728;
  ushort_t* w3h_dr0 = (ushort_t*)(ws + o); o += 73728;
  ushort_t* w3l_dr0 = (ushort_t*)(ws + o); o += 73728;
  ushort_t* w3h_dr1 = (ushort_t*)(ws + o); o += 73728;
  ushort_t* w3l_dr1 = (ushort_t*)(ws + o); o += 73728;

  float* fout = (float*)d_out;

  #define GB(n) (((n) + 255) / 256)
  // zero activation region + smalls (halos + counters)
  hipMemsetAsync(ws, 0, WT_OFF * sizeof(float), stream);

  k_wt_conv<<<GB(3 * 64 * 16), 256, 0, stream>>>(enc_w0, wt_enc0, 3, 64, 16);
  k_wt_conv<<<GB(64 * 256), 256, 0, stream>>>(er0w2, wt_er0w2, 64, 256, 1);
  k_wt_conv<<<GB(64 * 256), 256, 0, stream>>>(er1w2, wt_er1w2, 64, 256, 1);
  k_wt_conv<<<GB(256 * 64), 256, 0, stream>>>(eadj_w, wt_eadj, 256, 64, 1);
  k_wt_conv<<<GB(64 * 256), 256, 0, stream>>>(dadj_w, wt_dadj, 64, 256, 1);
  k_wt_conv<<<GB(64 * 256), 256, 0, stream>>>(dr0w2, wt_dr0w2, 64, 256, 1);
  k_wt_conv<<<GB(64 * 256), 256, 0, stream>>>(dr1w2, wt_dr1w2, 64, 256, 1);
  k_wtb<<<GB(524288), 256, 0, stream>>>(tw0, wbT0, 256, 128);
  k_wtb<<<GB(131072), 256, 0, stream>>>(tw1, wbT1, 128, 64);
  k_wtb<<<GB(32768), 256, 0, stream>>>(tw2, wbT2, 64, 32);
  k_wsplit<<<GB(131072), 256, 0, stream>>>(enc_w1, wsh1, wsl1, 131072);
  k_wsplit<<<GB(524288), 256, 0, stream>>>(enc_w2, wsh2, wsl2, 524288);
  k_wt3split<<<GB(147456), 256, 0, stream>>>(er0w1, w3h_er0, w3l_er0);
  k_wt3split<<<GB(147456), 256, 0, stream>>>(er1w1, w3h_er1, w3l_er1);
  k_wt3split<<<GB(147456), 256, 0, stream>>>(dr0w1, w3h_dr0, w3l_dr0);
  k_wt3split<<<GB(147456), 256, 0, stream>>>(dr1w1, w3h_dr1, w3l_dr1);
  k_cbt<<<4, 256, 0, stream>>>(codebook, cbT, cnorm);

  // ---------- encoder (split-bf16 MFMA ~ fp32 accuracy; protects VQ argmin) ----------
  k_conv4s2_s3<<<dim3(16, 4, 32), 256, 0, stream>>>(x, wt_enc0, enc_b0, A);
  k_conv4s2_mfma<6, 64, 128, 130, 16900, 66, 4356>
      <<<dim3(64, 2, 32), 256, 0, stream>>>(A, wsh1, wsl1, enc_b1, Bb);
  // A now dead -> zero C+D region (halos for enc2/res outputs)
  hipMemsetAsync(ws, 0, (size_t)18939904 * sizeof(float), stream);
  k_conv4s2_mfma<5, 128, 256, 66, 4356, 34, 1156>
      <<<dim3(16, 4, 32), 256, 0, stream>>>(Bb, wsh2, wsl2, enc_b2, C);
  k_conv3x3_mfma<<<dim3(16, 1, 32), 512, 0, stream>>>(C, w3h_er0, w3l_er0, er0b1, E);
  k_conv1x1_px<1, 1, 0, 1><<<dim3(4, 16, 32), 256, 0, stream>>>(E, wt_er0w2, er0b2, C, Dq, 64, 256);
  k_conv3x3_mfma<<<dim3(16, 1, 32), 512, 0, stream>>>(Dq, w3h_er1, w3l_er1, er1b1, E);
  k_conv1x1_px<1, 1, 0, 1><<<dim3(4, 16, 32), 256, 0, stream>>>(E, wt_er1w2, er1b2, Dq, C, 64, 256);
  k_conv1x1_px<0, 0, 1, 0><<<dim3(4, 4, 32), 256, 0, stream>>>(C, wt_eadj, eadj_b, nullptr, E, 256, 64);
  // ---------- VQ (fp32 exact) ----------
  k_vq<<<2048, 256, 0, stream>>>(E, cbT, cnorm, codebook, Q, counts, sumsq);
  // ---------- decoder ----------
  k_conv1x1_px<0, 0, 0, 1><<<dim3(4, 16, 32), 256, 0, stream>>>(Q, wt_dadj, dadj_b, nullptr, C, 64, 256);
  k_conv3x3_mfma<<<dim3(16, 1, 32), 512, 0, stream>>>(C, w3h_dr0, w3l_dr0, dr0b1, E);
  k_conv1x1_px<1, 1, 0, 1><<<dim3(4, 16, 32), 256, 0, stream>>>(E, wt_dr0w2, dr0b2, C, Dq, 64, 256);
  k_conv3x3_mfma<<<dim3(16, 1, 32), 512, 0, stream>>>(Dq, w3h_dr1, w3l_dr1, dr1b1, E);
  k_conv1x1_px<1, 1, 0, 1><<<dim3(4, 16, 32), 256, 0, stream>>>(E, wt_dr1w2, dr1b2, Dq, C, 64, 256);
  // MFMA bf16 transposed convs (decoder only)
  k_tconv_mfma<64, 64, 5, 256, 128, 34, 1156, 66, 4356, 0, 2>
      <<<dim3(16, 8, 32), 256, 0, stream>>>(C, wbT0, tb0, nullptr, nullptr, Bb);
  // C/D/E/Q dead -> zero A region (halos for tconv1 output)
  hipMemsetAsync(ws, 0, (size_t)34611200 * sizeof(float), stream);
  k_tconv_mfma<64, 64, 6, 128, 64, 66, 4356, 130, 16900, 0, 2>
      <<<dim3(64, 4, 32), 256, 0, stream>>>(Bb, wbT1, tb1, nullptr, nullptr, A);
  k_tconv_mfma<128, 32, 7, 64, 32, 130, 16900, 0, 0, 1, 1>
      <<<dim3(128, 4, 32), 256, 0, stream>>>(A, wbT2, tb2, out_w, out_b, fout);
  k_final<<<1, 256, 0, stream>>>(counts, sumsq, fout + 6291456);
  #undef GB
}